// Round 13
// baseline (330.666 us; speedup 1.0000x reference)
//
#include <hip/hip_runtime.h>
#include <hip/hip_bf16.h>

// GINE on MI355X — fp32 inputs/outputs; bf16 MFMA internals.
static const int NN = 100000;   // nodes
static const int NE = 1600000;  // edges
static const int NG = 512;      // graphs
static const int NB = 391;      // coarse buckets of 256 nodes (dst >> 8)
static const int PS = 4608;     // pairs region per bucket (mean 4096 + 8 sigma)
static const int CS = 4624;     // csr region per bucket (PS + 16 zero-fill slack)

typedef __attribute__((ext_vector_type(8))) short shortx8;
typedef __attribute__((ext_vector_type(4))) float floatx4;

__device__ __forceinline__ float bf2f(unsigned short u) {
  union { unsigned int i; float f; } v; v.i = ((unsigned int)u) << 16; return v.f;
}
__device__ __forceinline__ unsigned short f2bf(float f) {
  union { float f; unsigned int i; } v; v.f = f;
  return (unsigned short)((v.i + 0x7FFFu + ((v.i >> 16) & 1u)) >> 16);
}
__device__ __forceinline__ float elu_fast(float v) {
  return v > 0.f ? v : (__builtin_amdgcn_exp2f(v * 1.44269504f) - 1.f);
}

// ---- one prep kernel ----------------------------------------------------
// blocks 0..7: et1 | 8..483: M0 | 484..867: weight swizzle | 868..883: zero hgf
// | 884: bcursor init (fixed per-bucket bases).
__global__ void k_prep(const float* __restrict__ bond,
                       const float* __restrict__ we0, const float* __restrict__ be0,
                       const float* __restrict__ we1, const float* __restrict__ be1,
                       const float* __restrict__ atom,
                       float* __restrict__ et1, float* __restrict__ M0,
                       float* __restrict__ hgf, int* __restrict__ bcursor,
                       const float* __restrict__ s0, const float* __restrict__ s1,
                       const float* __restrict__ s2, const float* __restrict__ s3,
                       const float* __restrict__ s4, const float* __restrict__ s5,
                       unsigned short* __restrict__ d0, unsigned short* __restrict__ d1,
                       unsigned short* __restrict__ d2, unsigned short* __restrict__ d3,
                       unsigned short* __restrict__ d4, unsigned short* __restrict__ d5) {
  int blk = blockIdx.x, t = threadIdx.x;
  if (blk < 8) {                      // et1[16][128] = bond@we1 + be1
    int i = blk * 256 + t;
    int b = i >> 7, c = i & 127;
    float acc = be1[c];
    for (int k = 0; k < 64; ++k) acc += bond[b * 64 + k] * we1[k * 128 + c];
    et1[i] = acc;
  } else if (blk < 484) {             // M0[(a*16+b)*64+c] = relu(atom + bond@we0 + be0)
    int i = (blk - 8) * 256 + t;      // 476*256 == 119*16*64
    int c = i & 63, b = (i >> 6) & 15, a = i >> 10;
    float acc = be0[c];
    for (int k = 0; k < 64; ++k) acc += bond[b * 64 + k] * we0[k * 64 + c];
    acc += atom[a * 64 + c];
    M0[i] = acc > 0.f ? acc : 0.f;
  } else if (blk < 868) {             // weight swizzle into MFMA B-frag order
    int task = (blk - 484) >> 6;
    int i = ((blk - 484) & 63) * 256 + t;
    const float* w; unsigned short* wz; int K;
    switch (task) {
      case 0: w = s0; wz = d0; K = 64; break;
      case 1: w = s1; wz = d1; K = 128; break;
      case 2: w = s2; wz = d2; K = 128; break;
      case 3: w = s3; wz = d3; K = 128; break;
      case 4: w = s4; wz = d4; K = 128; break;
      default: w = s5; wz = d5; K = 128; break;
    }
    if (i >= K * 128) return;
    int j = i & 7, lane = (i >> 3) & 63, ct = (i >> 9) & 7, s = i >> 12;
    int k = s * 32 + (lane >> 4) * 8 + j;
    int m = ct * 16 + (lane & 15);
    wz[i] = f2bf(w[k * 128 + m]);
  } else if (blk < 884) {             // zero hgf (512*128 floats)
    int base = (blk - 868) * 4096;
#pragma unroll
    for (int k = 0; k < 16; ++k) hgf[base + k * 256 + t] = 0.f;
  } else {                            // bcursor fixed bases
    if (t < NB) bcursor[t] = t * PS;
    int u = t + 256;
    if (u < NB) bcursor[u] = u * PS;
  }
}

// Pass B: bin 4096-edge chunks by coarse bucket into fixed per-bucket regions.
__global__ void k_bin(const int* __restrict__ src, const int* __restrict__ dstp,
                      const int* __restrict__ ea, const int* __restrict__ x_idx,
                      int* __restrict__ bcursor, uint2* __restrict__ pairs) {
  __shared__ int cnt[512];
  __shared__ int incl[512];
  __shared__ int cur[NB];
  __shared__ int rbase[NB];
  __shared__ uint2 stage[4096];
  int t = threadIdx.x;
  int e0 = blockIdx.x * 4096;
  int ecnt = NE - e0; if (ecnt > 4096) ecnt = 4096;
  cnt[t] = 0; cnt[t + 256] = 0;
  __syncthreads();
  for (int k = 0; k < 16; ++k) {
    int i = k * 256 + t;
    if (i < ecnt) atomicAdd(&cnt[dstp[e0 + i] >> 8], 1);
  }
  __syncthreads();
  incl[t] = cnt[t]; incl[t + 256] = cnt[t + 256];
  __syncthreads();
  for (int d = 1; d < 512; d <<= 1) {
    int v0 = (t >= d) ? incl[t - d] : 0;
    int v1 = (t + 256 >= d) ? incl[t + 256 - d] : 0;
    __syncthreads();
    incl[t] += v0; incl[t + 256] += v1;
    __syncthreads();
  }
  if (t < NB) { cur[t] = incl[t] - cnt[t]; if (cnt[t]) rbase[t] = atomicAdd(&bcursor[t], cnt[t]); }
  int u = t + 256;
  if (u < NB) { cur[u] = incl[u] - cnt[u]; if (cnt[u]) rbase[u] = atomicAdd(&bcursor[u], cnt[u]); }
  __syncthreads();
  for (int k = 0; k < 16; ++k) {
    int i = k * 256 + t;
    if (i < ecnt) {
      int e = e0 + i;
      int d = dstp[e];
      int s = src[e];
      unsigned int pk = (unsigned int)s | ((unsigned int)(x_idx[s] * 16 + ea[e]) << 17);
      int p = atomicAdd(&cur[d >> 8], 1);
      stage[p] = make_uint2((unsigned int)d, pk);
    }
  }
  __syncthreads();
  for (int j = t; j < ecnt; j += 256) {   // bucket from dst — no search
    uint2 p = stage[j];
    int b = (int)(p.x >> 8);
    int excl = incl[b] - cnt[b];
    pairs[rbase[b] + (j - excl)] = p;
  }
}

// Pass C: fine counting-sort per bucket; absolute offs + cnts; 16 zero slots.
__global__ void k_fine(const uint2* __restrict__ pairs, const int* __restrict__ bcursor,
                       int* __restrict__ offs, int* __restrict__ cnts,
                       unsigned int* __restrict__ csr0, unsigned int* __restrict__ csr1) {
  __shared__ int cnt[256];
  __shared__ int incl[256];
  __shared__ int cur[256];
  int b = blockIdx.x;
  int t = threadIdx.x;
  int start = b * PS;
  int endv = bcursor[b];
  int cbase = b * CS;
  int base_n = b << 8;
  cnt[t] = 0;
  __syncthreads();
  for (int j = start + t; j < endv; j += 256)
    atomicAdd(&cnt[(int)pairs[j].x - base_n], 1);
  __syncthreads();
  incl[t] = cnt[t];
  __syncthreads();
  for (int d = 1; d < 256; d <<= 1) {
    int v = (t >= d) ? incl[t - d] : 0;
    __syncthreads();
    incl[t] += v;
    __syncthreads();
  }
  int excl = incl[t] - cnt[t];
  cur[t] = excl;
  int node = base_n + t;
  if (node < NN) { offs[node] = cbase + excl; cnts[node] = cnt[t]; }
  __syncthreads();
  for (int j = start + t; j < endv; j += 256) {
    uint2 p = pairs[j];
    int pos = cbase + atomicAdd(&cur[(int)p.x - base_n], 1);
    unsigned int pk = p.y;
    unsigned int idx17 = pk >> 17;
    csr0[pos] = idx17 << 8;
    csr1[pos] = ((pk & 0x1FFFFu) << 8) | (idx17 & 15u);
  }
  __syncthreads();
  int total = incl[255];
  if (t < 16) { csr0[cbase + total + t] = 0u; csr1[cbase + total + t] = 0u; }
}

// ---- aggregation layer 0: wave per node, lane = channel; masked unroll-16.
__global__ __launch_bounds__(256) void k_agg0(
    const int* __restrict__ x_idx, const float* __restrict__ atom,
    const float* __restrict__ M0, const int* __restrict__ offs,
    const int* __restrict__ cnts,
    const unsigned int* __restrict__ csr0, unsigned short* __restrict__ h0) {
  int t = threadIdx.x, lane = t & 63;
  int n = __builtin_amdgcn_readfirstlane(blockIdx.x * 4 + (t >> 6));
  if (n >= NN) return;
  int s = offs[n], e = s + cnts[n];
  const char* Mb = (const char*)M0;
  unsigned int voff = (unsigned int)lane * 4u;
  float acc = *(const float*)((const char*)atom + ((size_t)(unsigned)x_idx[n] << 8) + voff);
  for (int i = s; i < e; i += 16) {
    unsigned int q0 = csr0[i + 0],  q1 = csr0[i + 1],  q2 = csr0[i + 2],  q3 = csr0[i + 3];
    unsigned int q4 = csr0[i + 4],  q5 = csr0[i + 5],  q6 = csr0[i + 6],  q7 = csr0[i + 7];
    unsigned int q8 = csr0[i + 8],  q9 = csr0[i + 9],  qa = csr0[i + 10], qb = csr0[i + 11];
    unsigned int qc = csr0[i + 12], qd = csr0[i + 13], qe = csr0[i + 14], qf = csr0[i + 15];
    float m1 = (i + 1 < e) ? 1.f : 0.f,  m2 = (i + 2 < e) ? 1.f : 0.f;
    float m3 = (i + 3 < e) ? 1.f : 0.f,  m4 = (i + 4 < e) ? 1.f : 0.f;
    float m5 = (i + 5 < e) ? 1.f : 0.f,  m6 = (i + 6 < e) ? 1.f : 0.f;
    float m7 = (i + 7 < e) ? 1.f : 0.f,  m8 = (i + 8 < e) ? 1.f : 0.f;
    float m9 = (i + 9 < e) ? 1.f : 0.f,  ma = (i + 10 < e) ? 1.f : 0.f;
    float mb = (i + 11 < e) ? 1.f : 0.f, mc = (i + 12 < e) ? 1.f : 0.f;
    float md = (i + 13 < e) ? 1.f : 0.f, me = (i + 14 < e) ? 1.f : 0.f;
    float mf = (i + 15 < e) ? 1.f : 0.f;
    float v0 = *(const float*)(Mb + q0 + voff);
    float v1 = *(const float*)(Mb + q1 + voff);
    float v2 = *(const float*)(Mb + q2 + voff);
    float v3 = *(const float*)(Mb + q3 + voff);
    float v4 = *(const float*)(Mb + q4 + voff);
    float v5 = *(const float*)(Mb + q5 + voff);
    float v6 = *(const float*)(Mb + q6 + voff);
    float v7 = *(const float*)(Mb + q7 + voff);
    float v8 = *(const float*)(Mb + q8 + voff);
    float v9 = *(const float*)(Mb + q9 + voff);
    float va = *(const float*)(Mb + qa + voff);
    float vb = *(const float*)(Mb + qb + voff);
    float vc = *(const float*)(Mb + qc + voff);
    float vd = *(const float*)(Mb + qd + voff);
    float ve = *(const float*)(Mb + qe + voff);
    float vf = *(const float*)(Mb + qf + voff);
    acc += v0;
    acc = fmaf(m1, v1, acc); acc = fmaf(m2, v2, acc);
    acc = fmaf(m3, v3, acc); acc = fmaf(m4, v4, acc);
    acc = fmaf(m5, v5, acc); acc = fmaf(m6, v6, acc);
    acc = fmaf(m7, v7, acc); acc = fmaf(m8, v8, acc);
    acc = fmaf(m9, v9, acc); acc = fmaf(ma, va, acc);
    acc = fmaf(mb, vb, acc); acc = fmaf(mc, vc, acc);
    acc = fmaf(md, vd, acc); acc = fmaf(me, ve, acc);
    acc = fmaf(mf, vf, acc);
  }
  h0[(size_t)n * 64 + lane] = f2bf(acc);
}

// ---- aggregation layer 1: wave per node, lane = 2 channels; et1 in LDS;
// masked unroll-16 (16 concurrent row gathers per wave).
__global__ __launch_bounds__(256) void k_agg1(
    const unsigned short* __restrict__ x1, const float* __restrict__ et1,
    const int* __restrict__ offs, const int* __restrict__ cnts,
    const unsigned int* __restrict__ csr1, unsigned short* __restrict__ h1) {
  __shared__ float etl[2048];      // 16 rows x 128 ch, 8 KB
  int t = threadIdx.x;
#pragma unroll
  for (int k = 0; k < 8; ++k) etl[k * 256 + t] = et1[k * 256 + t];
  __syncthreads();
  int lane = t & 63;
  int n = __builtin_amdgcn_readfirstlane(blockIdx.x * 4 + (t >> 6));
  if (n >= NN) return;
  int s = offs[n], e = s + cnts[n];
  const char* xb = (const char*)x1;
  unsigned int voff = (unsigned int)lane * 4u;
  const char* etb = (const char*)etl + (size_t)lane * 8u;
  unsigned int xv = *(const unsigned int*)(xb + ((size_t)(unsigned)n << 8) + voff);
  float ax = bf2f((unsigned short)(xv & 0xFFFF));
  float ay = bf2f((unsigned short)(xv >> 16));
  for (int i = s; i < e; i += 16) {
    unsigned int q0 = csr1[i + 0],  q1 = csr1[i + 1],  q2 = csr1[i + 2],  q3 = csr1[i + 3];
    unsigned int q4 = csr1[i + 4],  q5 = csr1[i + 5],  q6 = csr1[i + 6],  q7 = csr1[i + 7];
    unsigned int q8 = csr1[i + 8],  q9 = csr1[i + 9],  qa = csr1[i + 10], qb = csr1[i + 11];
    unsigned int qc = csr1[i + 12], qd = csr1[i + 13], qe = csr1[i + 14], qf = csr1[i + 15];
    float m1 = (i + 1 < e) ? 1.f : 0.f,  m2 = (i + 2 < e) ? 1.f : 0.f;
    float m3 = (i + 3 < e) ? 1.f : 0.f,  m4 = (i + 4 < e) ? 1.f : 0.f;
    float m5 = (i + 5 < e) ? 1.f : 0.f,  m6 = (i + 6 < e) ? 1.f : 0.f;
    float m7 = (i + 7 < e) ? 1.f : 0.f,  m8 = (i + 8 < e) ? 1.f : 0.f;
    float m9 = (i + 9 < e) ? 1.f : 0.f,  ma = (i + 10 < e) ? 1.f : 0.f;
    float mb = (i + 11 < e) ? 1.f : 0.f, mc = (i + 12 < e) ? 1.f : 0.f;
    float md = (i + 13 < e) ? 1.f : 0.f, me = (i + 14 < e) ? 1.f : 0.f;
    float mf = (i + 15 < e) ? 1.f : 0.f;
    unsigned int v0 = *(const unsigned int*)(xb + (q0 & 0xFFFFFF00u) + voff);
    unsigned int v1 = *(const unsigned int*)(xb + (q1 & 0xFFFFFF00u) + voff);
    unsigned int v2 = *(const unsigned int*)(xb + (q2 & 0xFFFFFF00u) + voff);
    unsigned int v3 = *(const unsigned int*)(xb + (q3 & 0xFFFFFF00u) + voff);
    unsigned int v4 = *(const unsigned int*)(xb + (q4 & 0xFFFFFF00u) + voff);
    unsigned int v5 = *(const unsigned int*)(xb + (q5 & 0xFFFFFF00u) + voff);
    unsigned int v6 = *(const unsigned int*)(xb + (q6 & 0xFFFFFF00u) + voff);
    unsigned int v7 = *(const unsigned int*)(xb + (q7 & 0xFFFFFF00u) + voff);
    unsigned int v8 = *(const unsigned int*)(xb + (q8 & 0xFFFFFF00u) + voff);
    unsigned int v9 = *(const unsigned int*)(xb + (q9 & 0xFFFFFF00u) + voff);
    unsigned int va = *(const unsigned int*)(xb + (qa & 0xFFFFFF00u) + voff);
    unsigned int vb = *(const unsigned int*)(xb + (qb & 0xFFFFFF00u) + voff);
    unsigned int vc = *(const unsigned int*)(xb + (qc & 0xFFFFFF00u) + voff);
    unsigned int vd = *(const unsigned int*)(xb + (qd & 0xFFFFFF00u) + voff);
    unsigned int ve = *(const unsigned int*)(xb + (qe & 0xFFFFFF00u) + voff);
    unsigned int vf = *(const unsigned int*)(xb + (qf & 0xFFFFFF00u) + voff);
    float2 e0 = *(const float2*)(etb + ((q0 & 15u) << 9));
    float2 e1 = *(const float2*)(etb + ((q1 & 15u) << 9));
    float2 e2 = *(const float2*)(etb + ((q2 & 15u) << 9));
    float2 e3 = *(const float2*)(etb + ((q3 & 15u) << 9));
    float2 e4 = *(const float2*)(etb + ((q4 & 15u) << 9));
    float2 e5 = *(const float2*)(etb + ((q5 & 15u) << 9));
    float2 e6 = *(const float2*)(etb + ((q6 & 15u) << 9));
    float2 e7 = *(const float2*)(etb + ((q7 & 15u) << 9));
    float mx, my;
    mx = bf2f((unsigned short)(v0 & 0xFFFF)) + e0.x; my = bf2f((unsigned short)(v0 >> 16)) + e0.y;
    ax += fmaxf(mx, 0.f); ay += fmaxf(my, 0.f);
    mx = bf2f((unsigned short)(v1 & 0xFFFF)) + e1.x; my = bf2f((unsigned short)(v1 >> 16)) + e1.y;
    ax = fmaf(m1, fmaxf(mx, 0.f), ax); ay = fmaf(m1, fmaxf(my, 0.f), ay);
    mx = bf2f((unsigned short)(v2 & 0xFFFF)) + e2.x; my = bf2f((unsigned short)(v2 >> 16)) + e2.y;
    ax = fmaf(m2, fmaxf(mx, 0.f), ax); ay = fmaf(m2, fmaxf(my, 0.f), ay);
    mx = bf2f((unsigned short)(v3 & 0xFFFF)) + e3.x; my = bf2f((unsigned short)(v3 >> 16)) + e3.y;
    ax = fmaf(m3, fmaxf(mx, 0.f), ax); ay = fmaf(m3, fmaxf(my, 0.f), ay);
    mx = bf2f((unsigned short)(v4 & 0xFFFF)) + e4.x; my = bf2f((unsigned short)(v4 >> 16)) + e4.y;
    ax = fmaf(m4, fmaxf(mx, 0.f), ax); ay = fmaf(m4, fmaxf(my, 0.f), ay);
    mx = bf2f((unsigned short)(v5 & 0xFFFF)) + e5.x; my = bf2f((unsigned short)(v5 >> 16)) + e5.y;
    ax = fmaf(m5, fmaxf(mx, 0.f), ax); ay = fmaf(m5, fmaxf(my, 0.f), ay);
    mx = bf2f((unsigned short)(v6 & 0xFFFF)) + e6.x; my = bf2f((unsigned short)(v6 >> 16)) + e6.y;
    ax = fmaf(m6, fmaxf(mx, 0.f), ax); ay = fmaf(m6, fmaxf(my, 0.f), ay);
    mx = bf2f((unsigned short)(v7 & 0xFFFF)) + e7.x; my = bf2f((unsigned short)(v7 >> 16)) + e7.y;
    ax = fmaf(m7, fmaxf(mx, 0.f), ax); ay = fmaf(m7, fmaxf(my, 0.f), ay);
    float2 e8 = *(const float2*)(etb + ((q8 & 15u) << 9));
    float2 e9 = *(const float2*)(etb + ((q9 & 15u) << 9));
    float2 ea = *(const float2*)(etb + ((qa & 15u) << 9));
    float2 eb = *(const float2*)(etb + ((qb & 15u) << 9));
    float2 ec = *(const float2*)(etb + ((qc & 15u) << 9));
    float2 ed = *(const float2*)(etb + ((qd & 15u) << 9));
    float2 ee = *(const float2*)(etb + ((qe & 15u) << 9));
    float2 ef = *(const float2*)(etb + ((qf & 15u) << 9));
    mx = bf2f((unsigned short)(v8 & 0xFFFF)) + e8.x; my = bf2f((unsigned short)(v8 >> 16)) + e8.y;
    ax = fmaf(m8, fmaxf(mx, 0.f), ax); ay = fmaf(m8, fmaxf(my, 0.f), ay);
    mx = bf2f((unsigned short)(v9 & 0xFFFF)) + e9.x; my = bf2f((unsigned short)(v9 >> 16)) + e9.y;
    ax = fmaf(m9, fmaxf(mx, 0.f), ax); ay = fmaf(m9, fmaxf(my, 0.f), ay);
    mx = bf2f((unsigned short)(va & 0xFFFF)) + ea.x; my = bf2f((unsigned short)(va >> 16)) + ea.y;
    ax = fmaf(ma, fmaxf(mx, 0.f), ax); ay = fmaf(ma, fmaxf(my, 0.f), ay);
    mx = bf2f((unsigned short)(vb & 0xFFFF)) + eb.x; my = bf2f((unsigned short)(vb >> 16)) + eb.y;
    ax = fmaf(mb, fmaxf(mx, 0.f), ax); ay = fmaf(mb, fmaxf(my, 0.f), ay);
    mx = bf2f((unsigned short)(vc & 0xFFFF)) + ec.x; my = bf2f((unsigned short)(vc >> 16)) + ec.y;
    ax = fmaf(mc, fmaxf(mx, 0.f), ax); ay = fmaf(mc, fmaxf(my, 0.f), ay);
    mx = bf2f((unsigned short)(vd & 0xFFFF)) + ed.x; my = bf2f((unsigned short)(vd >> 16)) + ed.y;
    ax = fmaf(md, fmaxf(mx, 0.f), ax); ay = fmaf(md, fmaxf(my, 0.f), ay);
    mx = bf2f((unsigned short)(ve & 0xFFFF)) + ee.x; my = bf2f((unsigned short)(ve >> 16)) + ee.y;
    ax = fmaf(me, fmaxf(mx, 0.f), ax); ay = fmaf(me, fmaxf(my, 0.f), ay);
    mx = bf2f((unsigned short)(vf & 0xFFFF)) + ef.x; my = bf2f((unsigned short)(vf >> 16)) + ef.y;
    ax = fmaf(mf, fmaxf(mx, 0.f), ax); ay = fmaf(mf, fmaxf(my, 0.f), ay);
  }
  unsigned int o = (unsigned int)f2bf(ax) | ((unsigned int)f2bf(ay) << 16);
  *(unsigned int*)(h1 + (size_t)n * 128 + lane * 2) = o;
}

// ---- double-GEMM MLP: 128 rows/block (2 tiles), w2 in LDS, one barrier,
// wave-private tls, coalesced dwordx4 stores. No pooling epilogue.
template <int K1>
__global__ __launch_bounds__(256) void k_mlp_t(
    const unsigned short* __restrict__ in,
    const unsigned short* __restrict__ w1z, const float* __restrict__ b1,
    const unsigned short* __restrict__ w2z, const float* __restrict__ b2,
    unsigned short* __restrict__ outb, int N) {
  __shared__ unsigned short tls[4][16][136];   // wave-private mid/out tile
  __shared__ unsigned short b2s[16384];        // 32 KB staged w2 frags
  int t = threadIdx.x;
  int lane = t & 63;
  int wave = t >> 6;
  int rlo = lane & 15, quad = lane >> 4;

#pragma unroll
  for (int k = 0; k < 8; ++k)
    *(shortx8*)&b2s[(k * 256 + t) * 8] = *(const shortx8*)&w2z[(k * 256 + t) * 8];

  float bm1[8], bm2[8];
#pragma unroll
  for (int ct = 0; ct < 8; ++ct) { bm1[ct] = b1[ct * 16 + rlo]; bm2[ct] = b2[ct * 16 + rlo]; }

  __syncthreads();   // b2s ready (only barrier)

#pragma unroll
  for (int t2 = 0; t2 < 2; ++t2) {
    int row0 = blockIdx.x * 128 + t2 * 64 + wave * 16;
    int arow = row0 + rlo;

    floatx4 acc[8];
#pragma unroll
    for (int ct = 0; ct < 8; ++ct) { acc[ct][0]=0.f; acc[ct][1]=0.f; acc[ct][2]=0.f; acc[ct][3]=0.f; }
    const int NS = K1 >> 5;
#pragma unroll
    for (int s = 0; s < NS; ++s) {
      shortx8 a = {0,0,0,0,0,0,0,0};
      if (arow < N) a = *(const shortx8*)(in + (size_t)arow * K1 + s * 32 + quad * 8);
      const unsigned short* wp = w1z + ((size_t)(s * 8) * 64 + lane) * 8;
#pragma unroll
      for (int ct = 0; ct < 8; ++ct) {
        shortx8 b = *(const shortx8*)(wp + ct * 512);
        acc[ct] = __builtin_amdgcn_mfma_f32_16x16x32_bf16(a, b, acc[ct], 0, 0, 0);
      }
    }
#pragma unroll
    for (int ct = 0; ct < 8; ++ct) {
#pragma unroll
      for (int r = 0; r < 4; ++r) {
        float v = elu_fast(acc[ct][r] + bm1[ct]);
        tls[wave][quad * 4 + r][ct * 16 + rlo] = f2bf(v);
      }
    }
    // no barrier: tls[wave] is wave-private; DS ops are wave-ordered.

    floatx4 acc2[8];
#pragma unroll
    for (int ct = 0; ct < 8; ++ct) { acc2[ct][0]=0.f; acc2[ct][1]=0.f; acc2[ct][2]=0.f; acc2[ct][3]=0.f; }
#pragma unroll
    for (int s = 0; s < 4; ++s) {
      shortx8 a = *(const shortx8*)&tls[wave][rlo][s * 32 + quad * 8];
      const unsigned short* wp = &b2s[((s * 8) * 64 + lane) * 8];
#pragma unroll
      for (int ct = 0; ct < 8; ++ct) {
        shortx8 b = *(const shortx8*)(wp + ct * 512);
        acc2[ct] = __builtin_amdgcn_mfma_f32_16x16x32_bf16(a, b, acc2[ct], 0, 0, 0);
      }
    }
#pragma unroll
    for (int ct = 0; ct < 8; ++ct) {
#pragma unroll
      for (int r = 0; r < 4; ++r) {
        float v = elu_fast(acc2[ct][r] + bm2[ct]);
        tls[wave][quad * 4 + r][ct * 16 + rlo] = f2bf(v);
      }
    }
    int srow = lane >> 2;           // 0..15
    int schunk = lane & 3;          // 0..3
    int grow = row0 + srow;
#pragma unroll
    for (int k = 0; k < 4; ++k) {
      int ch = schunk + k * 4;      // 16B chunk (8 cols)
      if (grow < N)
        *(shortx8*)(outb + (size_t)grow * 128 + ch * 8) =
            *(const shortx8*)&tls[wave][srow][ch * 8];
    }
  }
}

// ---- pooling (R7-proven): wave per 32-node chunk, lane = 2 channels.
__global__ __launch_bounds__(256) void k_pool(
    const unsigned short* __restrict__ x2, const int* __restrict__ batch,
    float* __restrict__ hgf) {
  int gt = blockIdx.x * 256 + threadIdx.x;
  int chunk = gt >> 6, lane = gt & 63;
  int n0 = chunk * 32;
  if (n0 >= NN) return;
  int nend = n0 + 32; if (nend > NN) nend = NN;
  float ax = 0.f, ay = 0.f;
  const unsigned short* xp = x2 + lane * 2;
  int gcur = batch[n0];
  for (int n = n0; n < nend; ++n) {
    int g = batch[n];
    if (g != gcur) {
      atomicAdd(&hgf[gcur * 128 + lane * 2], ax);
      atomicAdd(&hgf[gcur * 128 + lane * 2 + 1], ay);
      ax = 0.f; ay = 0.f; gcur = g;
    }
    unsigned int v = *(const unsigned int*)(xp + (size_t)n * 128);
    ax += bf2f((unsigned short)(v & 0xFFFF));
    ay += bf2f((unsigned short)(v >> 16));
  }
  atomicAdd(&hgf[gcur * 128 + lane * 2], ax);
  atomicAdd(&hgf[gcur * 128 + lane * 2 + 1], ay);
}

// ---- head MLP: A rows fp32 (pooled), out fp32 = (relu(in@l1+b))@l2+b
__global__ void k_head(const float* __restrict__ in,
                       const unsigned short* __restrict__ w1z, const float* __restrict__ b1,
                       const unsigned short* __restrict__ w2z, const float* __restrict__ b2,
                       float* __restrict__ outf, int N) {
  __shared__ unsigned short tls[4][16][136];
  int lane = threadIdx.x & 63;
  int wave = threadIdx.x >> 6;
  int row0 = blockIdx.x * 64 + wave * 16;
  int rlo = lane & 15, quad = lane >> 4;
  int arow = row0 + rlo;
  floatx4 acc[8];
#pragma unroll
  for (int ct = 0; ct < 8; ++ct) { acc[ct][0]=0.f; acc[ct][1]=0.f; acc[ct][2]=0.f; acc[ct][3]=0.f; }
#pragma unroll
  for (int s = 0; s < 4; ++s) {
    shortx8 a = {0,0,0,0,0,0,0,0};
    if (arow < N) {
      const float* rp = in + (size_t)arow * 128 + s * 32 + quad * 8;
      float4 f0 = *(const float4*)rp;
      float4 f1 = *(const float4*)(rp + 4);
      a[0] = (short)f2bf(f0.x); a[1] = (short)f2bf(f0.y);
      a[2] = (short)f2bf(f0.z); a[3] = (short)f2bf(f0.w);
      a[4] = (short)f2bf(f1.x); a[5] = (short)f2bf(f1.y);
      a[6] = (short)f2bf(f1.z); a[7] = (short)f2bf(f1.w);
    }
    const unsigned short* wp = w1z + ((size_t)(s * 8) * 64 + lane) * 8;
#pragma unroll
    for (int ct = 0; ct < 8; ++ct) {
      shortx8 b = *(const shortx8*)(wp + ct * 512);
      acc[ct] = __builtin_amdgcn_mfma_f32_16x16x32_bf16(a, b, acc[ct], 0, 0, 0);
    }
  }
#pragma unroll
  for (int ct = 0; ct < 8; ++ct) {
    float bm = b1[ct * 16 + rlo];
#pragma unroll
    for (int r = 0; r < 4; ++r) {
      float v = acc[ct][r] + bm;
      v = v > 0.f ? v : 0.f;  // relu
      tls[wave][quad * 4 + r][ct * 16 + rlo] = f2bf(v);
    }
  }
  __syncthreads();
  floatx4 acc2[8];
#pragma unroll
  for (int ct = 0; ct < 8; ++ct) { acc2[ct][0]=0.f; acc2[ct][1]=0.f; acc2[ct][2]=0.f; acc2[ct][3]=0.f; }
#pragma unroll
  for (int s = 0; s < 4; ++s) {
    shortx8 a = *(const shortx8*)&tls[wave][rlo][s * 32 + quad * 8];
    const unsigned short* wp = w2z + ((size_t)(s * 8) * 64 + lane) * 8;
#pragma unroll
    for (int ct = 0; ct < 8; ++ct) {
      shortx8 b = *(const shortx8*)(wp + ct * 512);
      acc2[ct] = __builtin_amdgcn_mfma_f32_16x16x32_bf16(a, b, acc2[ct], 0, 0, 0);
    }
  }
#pragma unroll
  for (int ct = 0; ct < 8; ++ct) {
    float bm = b2[ct * 16 + rlo];
#pragma unroll
    for (int r = 0; r < 4; ++r) {
      int rr = row0 + quad * 4 + r;
      if (rr < N) outf[(size_t)rr * 128 + ct * 16 + rlo] = acc2[ct][r] + bm;
    }
  }
}

extern "C" void kernel_launch(void* const* d_in, const int* in_sizes, int n_in,
                              void* d_out, int out_size, void* d_ws, size_t ws_size,
                              hipStream_t stream) {
  const int* x_idx  = (const int*)d_in[0];
  const int* e_src  = (const int*)d_in[1];
  const int* e_dst  = e_src + NE;
  const int* e_attr = (const int*)d_in[2];
  const int* batch  = (const int*)d_in[3];
  const float* atom = (const float*)d_in[4];
  const float* bond = (const float*)d_in[5];
  const float* we0  = (const float*)d_in[6];
  const float* be0  = (const float*)d_in[7];
  const float* w1_0 = (const float*)d_in[8];
  const float* b1_0 = (const float*)d_in[9];
  const float* w2_0 = (const float*)d_in[10];
  const float* b2_0 = (const float*)d_in[11];
  const float* we1  = (const float*)d_in[12];
  const float* be1  = (const float*)d_in[13];
  const float* w1_1 = (const float*)d_in[14];
  const float* b1_1 = (const float*)d_in[15];
  const float* w2_1 = (const float*)d_in[16];
  const float* b2_1 = (const float*)d_in[17];
  const float* l1w  = (const float*)d_in[18];
  const float* l1b  = (const float*)d_in[19];
  const float* l2w  = (const float*)d_in[20];
  const float* l2b  = (const float*)d_in[21];

  char* ws = (char*)d_ws;
  size_t off = 0;
  auto alloc = [&](size_t bytes) -> void* {
    void* p = ws + off;
    off = (off + bytes + 255) & ~(size_t)255;
    return p;
  };
  int* bcursor = (int*)alloc((size_t)NB * 4);
  int* offs    = (int*)alloc((size_t)NN * 4);
  int* cnts    = (int*)alloc((size_t)NN * 4);
  float* et1   = (float*)alloc(16 * 128 * 4);
  float* M0    = (float*)alloc((size_t)1904 * 64 * 4);
  float* hgf   = (float*)alloc((size_t)NG * 128 * 4);
  unsigned short* w1_0z = (unsigned short*)alloc(64 * 128 * 2);
  unsigned short* w2_0z = (unsigned short*)alloc(128 * 128 * 2);
  unsigned short* w1_1z = (unsigned short*)alloc(128 * 128 * 2);
  unsigned short* w2_1z = (unsigned short*)alloc(128 * 128 * 2);
  unsigned short* l1z   = (unsigned short*)alloc(128 * 128 * 2);
  unsigned short* l2z   = (unsigned short*)alloc(128 * 128 * 2);
  uint2* pairs = (uint2*)alloc((size_t)NB * PS * 8);       // dead after k_fine
  unsigned int* csr0 = (unsigned int*)alloc((size_t)NB * CS * 4);
  unsigned int* csr1 = (unsigned int*)alloc((size_t)NB * CS * 4);
  unsigned short* x1 = (unsigned short*)alloc((size_t)NN * 128 * 2);
  unsigned short* h1 = (unsigned short*)alloc((size_t)NN * 128 * 2);
  unsigned short* h0 = (unsigned short*)pairs;  // 12.8 MB alias: pairs dead before agg0
  unsigned short* x2 = h1;  // in-place mlp1 (wave reads own rows before writing)

  k_prep<<<885, 256, 0, stream>>>(bond, we0, be0, we1, be1, atom, et1, M0, hgf, bcursor,
                                  w1_0, w2_0, w1_1, w2_1, l1w, l2w,
                                  w1_0z, w2_0z, w1_1z, w2_1z, l1z, l2z);
  k_bin<<<(NE + 4095) / 4096, 256, 0, stream>>>(e_src, e_dst, e_attr, x_idx, bcursor, pairs);
  k_fine<<<NB, 256, 0, stream>>>(pairs, bcursor, offs, cnts, csr0, csr1);
  k_agg0<<<NN / 4, 256, 0, stream>>>(x_idx, atom, M0, offs, cnts, csr0, h0);
  k_mlp_t<64><<<(NN + 127) / 128, 256, 0, stream>>>(h0, w1_0z, b1_0, w2_0z, b2_0, x1, NN);
  k_agg1<<<NN / 4, 256, 0, stream>>>(x1, et1, offs, cnts, csr1, h1);
  k_mlp_t<128><<<(NN + 127) / 128, 256, 0, stream>>>(h1, w1_1z, b1_1, w2_1z, b2_1, x2, NN);
  k_pool<<<(((NN + 31) / 32) * 64 + 255) / 256, 256, 0, stream>>>(x2, batch, hgf);
  k_head<<<(NG + 63) / 64, 256, 0, stream>>>(hgf, l1z, l1b, l2z, l2b, (float*)d_out, NG);
}

// Round 14
// 325.945 us; speedup vs baseline: 1.0145x; 1.0145x over previous
//
#include <hip/hip_runtime.h>
#include <hip/hip_bf16.h>

// GINE on MI355X — fp32 inputs/outputs; bf16 MFMA internals.
static const int NN = 100000;   // nodes
static const int NE = 1600000;  // edges
static const int NG = 512;      // graphs
static const int NB = 391;      // coarse buckets of 256 nodes (dst >> 8)
static const int PS = 4608;     // pairs region per bucket (mean 4096 + 8 sigma)
static const int CS = 4624;     // csr region per bucket (PS + 16 zero-fill slack)

typedef __attribute__((ext_vector_type(8))) short shortx8;
typedef __attribute__((ext_vector_type(4))) float floatx4;

__device__ __forceinline__ float bf2f(unsigned short u) {
  union { unsigned int i; float f; } v; v.i = ((unsigned int)u) << 16; return v.f;
}
__device__ __forceinline__ unsigned short f2bf(float f) {
  union { float f; unsigned int i; } v; v.f = f;
  return (unsigned short)((v.i + 0x7FFFu + ((v.i >> 16) & 1u)) >> 16);
}
__device__ __forceinline__ float elu_fast(float v) {
  return v > 0.f ? v : (__builtin_amdgcn_exp2f(v * 1.44269504f) - 1.f);
}

// ---- one prep kernel ----------------------------------------------------
// blocks 0..7: et1 | 8..483: M0 (bf16) | 484..867: weight swizzle |
// 868..883: zero hgf | 884: bcursor init.
__global__ void k_prep(const float* __restrict__ bond,
                       const float* __restrict__ we0, const float* __restrict__ be0,
                       const float* __restrict__ we1, const float* __restrict__ be1,
                       const float* __restrict__ atom,
                       float* __restrict__ et1, unsigned short* __restrict__ M0,
                       float* __restrict__ hgf, int* __restrict__ bcursor,
                       const float* __restrict__ s0, const float* __restrict__ s1,
                       const float* __restrict__ s2, const float* __restrict__ s3,
                       const float* __restrict__ s4, const float* __restrict__ s5,
                       unsigned short* __restrict__ d0, unsigned short* __restrict__ d1,
                       unsigned short* __restrict__ d2, unsigned short* __restrict__ d3,
                       unsigned short* __restrict__ d4, unsigned short* __restrict__ d5) {
  int blk = blockIdx.x, t = threadIdx.x;
  if (blk < 8) {                      // et1[16][128] = bond@we1 + be1
    int i = blk * 256 + t;
    int b = i >> 7, c = i & 127;
    float acc = be1[c];
    for (int k = 0; k < 64; ++k) acc += bond[b * 64 + k] * we1[k * 128 + c];
    et1[i] = acc;
  } else if (blk < 484) {             // M0 (bf16) = relu(atom + bond@we0 + be0)
    int i = (blk - 8) * 256 + t;      // 476*256 == 119*16*64
    int c = i & 63, b = (i >> 6) & 15, a = i >> 10;
    float acc = be0[c];
    for (int k = 0; k < 64; ++k) acc += bond[b * 64 + k] * we0[k * 64 + c];
    acc += atom[a * 64 + c];
    M0[i] = f2bf(acc > 0.f ? acc : 0.f);
  } else if (blk < 868) {             // weight swizzle into MFMA B-frag order
    int task = (blk - 484) >> 6;
    int i = ((blk - 484) & 63) * 256 + t;
    const float* w; unsigned short* wz; int K;
    switch (task) {
      case 0: w = s0; wz = d0; K = 64; break;
      case 1: w = s1; wz = d1; K = 128; break;
      case 2: w = s2; wz = d2; K = 128; break;
      case 3: w = s3; wz = d3; K = 128; break;
      case 4: w = s4; wz = d4; K = 128; break;
      default: w = s5; wz = d5; K = 128; break;
    }
    if (i >= K * 128) return;
    int j = i & 7, lane = (i >> 3) & 63, ct = (i >> 9) & 7, s = i >> 12;
    int k = s * 32 + (lane >> 4) * 8 + j;
    int m = ct * 16 + (lane & 15);
    wz[i] = f2bf(w[k * 128 + m]);
  } else if (blk < 884) {             // zero hgf (512*128 floats)
    int base = (blk - 868) * 4096;
#pragma unroll
    for (int k = 0; k < 16; ++k) hgf[base + k * 256 + t] = 0.f;
  } else {                            // bcursor fixed bases
    if (t < NB) bcursor[t] = t * PS;
    int u = t + 256;
    if (u < NB) bcursor[u] = u * PS;
  }
}

// Pass B: bin 4096-edge chunks by coarse bucket into fixed per-bucket regions.
__global__ void k_bin(const int* __restrict__ src, const int* __restrict__ dstp,
                      const int* __restrict__ ea, const int* __restrict__ x_idx,
                      int* __restrict__ bcursor, uint2* __restrict__ pairs) {
  __shared__ int cnt[512];
  __shared__ int incl[512];
  __shared__ int cur[NB];
  __shared__ int rbase[NB];
  __shared__ uint2 stage[4096];
  int t = threadIdx.x;
  int e0 = blockIdx.x * 4096;
  int ecnt = NE - e0; if (ecnt > 4096) ecnt = 4096;
  cnt[t] = 0; cnt[t + 256] = 0;
  __syncthreads();
  for (int k = 0; k < 16; ++k) {
    int i = k * 256 + t;
    if (i < ecnt) atomicAdd(&cnt[dstp[e0 + i] >> 8], 1);
  }
  __syncthreads();
  incl[t] = cnt[t]; incl[t + 256] = cnt[t + 256];
  __syncthreads();
  for (int d = 1; d < 512; d <<= 1) {
    int v0 = (t >= d) ? incl[t - d] : 0;
    int v1 = (t + 256 >= d) ? incl[t + 256 - d] : 0;
    __syncthreads();
    incl[t] += v0; incl[t + 256] += v1;
    __syncthreads();
  }
  if (t < NB) { cur[t] = incl[t] - cnt[t]; if (cnt[t]) rbase[t] = atomicAdd(&bcursor[t], cnt[t]); }
  int u = t + 256;
  if (u < NB) { cur[u] = incl[u] - cnt[u]; if (cnt[u]) rbase[u] = atomicAdd(&bcursor[u], cnt[u]); }
  __syncthreads();
  for (int k = 0; k < 16; ++k) {
    int i = k * 256 + t;
    if (i < ecnt) {
      int e = e0 + i;
      int d = dstp[e];
      int s = src[e];
      unsigned int pk = (unsigned int)s | ((unsigned int)(x_idx[s] * 16 + ea[e]) << 17);
      int p = atomicAdd(&cur[d >> 8], 1);
      stage[p] = make_uint2((unsigned int)d, pk);
    }
  }
  __syncthreads();
  for (int j = t; j < ecnt; j += 256) {   // bucket from dst — no search
    uint2 p = stage[j];
    int b = (int)(p.x >> 8);
    int excl = incl[b] - cnt[b];
    pairs[rbase[b] + (j - excl)] = p;
  }
}

// Pass C: fine counting-sort per bucket; absolute offs + cnts; 16 zero slots.
//   csr0[i] = M0-row byte offset (bf16 rows: idx17*128)
//   csr1[i] = (src*256) | bond
__global__ void k_fine(const uint2* __restrict__ pairs, const int* __restrict__ bcursor,
                       int* __restrict__ offs, int* __restrict__ cnts,
                       unsigned int* __restrict__ csr0, unsigned int* __restrict__ csr1) {
  __shared__ int cnt[256];
  __shared__ int incl[256];
  __shared__ int cur[256];
  int b = blockIdx.x;
  int t = threadIdx.x;
  int start = b * PS;
  int endv = bcursor[b];
  int cbase = b * CS;
  int base_n = b << 8;
  cnt[t] = 0;
  __syncthreads();
  for (int j = start + t; j < endv; j += 256)
    atomicAdd(&cnt[(int)pairs[j].x - base_n], 1);
  __syncthreads();
  incl[t] = cnt[t];
  __syncthreads();
  for (int d = 1; d < 256; d <<= 1) {
    int v = (t >= d) ? incl[t - d] : 0;
    __syncthreads();
    incl[t] += v;
    __syncthreads();
  }
  int excl = incl[t] - cnt[t];
  cur[t] = excl;
  int node = base_n + t;
  if (node < NN) { offs[node] = cbase + excl; cnts[node] = cnt[t]; }
  __syncthreads();
  for (int j = start + t; j < endv; j += 256) {
    uint2 p = pairs[j];
    int pos = cbase + atomicAdd(&cur[(int)p.x - base_n], 1);
    unsigned int pk = p.y;
    unsigned int idx17 = pk >> 17;
    csr0[pos] = idx17 << 7;                 // bf16 M0 rows: 128 B
    csr1[pos] = ((pk & 0x1FFFFu) << 8) | (idx17 & 15u);
  }
  __syncthreads();
  int total = incl[255];
  if (t < 16) { csr0[cbase + total + t] = 0u; csr1[cbase + total + t] = 0u; }
}

// ---- aggregation layer 0: wave per node; bf16 M0, TWO edges per gather
// instruction (lanes 0-31 = edge 2k, lanes 32-63 = edge 2k+1, 2 ch/lane);
// per-half fp32 accumulate, shfl_xor(32) merge. Masked (zero-slot pads safe).
__global__ __launch_bounds__(256) void k_agg0(
    const int* __restrict__ x_idx, const float* __restrict__ atom,
    const unsigned short* __restrict__ M0, const int* __restrict__ offs,
    const int* __restrict__ cnts,
    const unsigned int* __restrict__ csr0, unsigned short* __restrict__ h0) {
  int t = threadIdx.x, lane = t & 63;
  int half = lane >> 5, c = lane & 31;
  int n = __builtin_amdgcn_readfirstlane(blockIdx.x * 4 + (t >> 6));
  if (n >= NN) return;
  int s = offs[n], e = s + cnts[n];
  const char* Mb = (const char*)M0;
  unsigned int voff = (unsigned int)c * 4u;
  float ax = 0.f, ay = 0.f;
  if (half == 0) {   // self term: h = x + agg
    float2 sv = *(const float2*)((const char*)atom +
                                 ((size_t)(unsigned)x_idx[n] << 8) + (size_t)c * 8u);
    ax = sv.x; ay = sv.y;
  }
  float fh = (float)half;
  for (int i = s; i < e; i += 16) {
    unsigned int a0 = csr0[i + 0],  b0 = csr0[i + 1];
    unsigned int a1 = csr0[i + 2],  b1 = csr0[i + 3];
    unsigned int a2 = csr0[i + 4],  b2 = csr0[i + 5];
    unsigned int a3 = csr0[i + 6],  b3 = csr0[i + 7];
    unsigned int a4 = csr0[i + 8],  b4 = csr0[i + 9];
    unsigned int a5 = csr0[i + 10], b5 = csr0[i + 11];
    unsigned int a6 = csr0[i + 12], b6 = csr0[i + 13];
    unsigned int a7 = csr0[i + 14], b7 = csr0[i + 15];
    unsigned int q0 = half ? b0 : a0, q1 = half ? b1 : a1;
    unsigned int q2 = half ? b2 : a2, q3 = half ? b3 : a3;
    unsigned int q4 = half ? b4 : a4, q5 = half ? b5 : a5;
    unsigned int q6 = half ? b6 : a6, q7 = half ? b7 : a7;
    // lane's edge index = i + 2k + half; first (k=0) lower-half always valid
    float m0 = (i + 0 + half < e) ? 1.f : 0.f;
    float m1 = (i + 2 + half < e) ? 1.f : 0.f;
    float m2 = (i + 4 + half < e) ? 1.f : 0.f;
    float m3 = (i + 6 + half < e) ? 1.f : 0.f;
    float m4 = (i + 8 + half < e) ? 1.f : 0.f;
    float m5 = (i + 10 + half < e) ? 1.f : 0.f;
    float m6 = (i + 12 + half < e) ? 1.f : 0.f;
    float m7 = (i + 14 + half < e) ? 1.f : 0.f;
    unsigned int v0 = *(const unsigned int*)(Mb + q0 + voff);
    unsigned int v1 = *(const unsigned int*)(Mb + q1 + voff);
    unsigned int v2 = *(const unsigned int*)(Mb + q2 + voff);
    unsigned int v3 = *(const unsigned int*)(Mb + q3 + voff);
    unsigned int v4 = *(const unsigned int*)(Mb + q4 + voff);
    unsigned int v5 = *(const unsigned int*)(Mb + q5 + voff);
    unsigned int v6 = *(const unsigned int*)(Mb + q6 + voff);
    unsigned int v7 = *(const unsigned int*)(Mb + q7 + voff);
    ax = fmaf(m0, bf2f((unsigned short)(v0 & 0xFFFF)), ax);
    ay = fmaf(m0, bf2f((unsigned short)(v0 >> 16)), ay);
    ax = fmaf(m1, bf2f((unsigned short)(v1 & 0xFFFF)), ax);
    ay = fmaf(m1, bf2f((unsigned short)(v1 >> 16)), ay);
    ax = fmaf(m2, bf2f((unsigned short)(v2 & 0xFFFF)), ax);
    ay = fmaf(m2, bf2f((unsigned short)(v2 >> 16)), ay);
    ax = fmaf(m3, bf2f((unsigned short)(v3 & 0xFFFF)), ax);
    ay = fmaf(m3, bf2f((unsigned short)(v3 >> 16)), ay);
    ax = fmaf(m4, bf2f((unsigned short)(v4 & 0xFFFF)), ax);
    ay = fmaf(m4, bf2f((unsigned short)(v4 >> 16)), ay);
    ax = fmaf(m5, bf2f((unsigned short)(v5 & 0xFFFF)), ax);
    ay = fmaf(m5, bf2f((unsigned short)(v5 >> 16)), ay);
    ax = fmaf(m6, bf2f((unsigned short)(v6 & 0xFFFF)), ax);
    ay = fmaf(m6, bf2f((unsigned short)(v6 >> 16)), ay);
    ax = fmaf(m7, bf2f((unsigned short)(v7 & 0xFFFF)), ax);
    ay = fmaf(m7, bf2f((unsigned short)(v7 >> 16)), ay);
  }
  ax += __shfl_xor(ax, 32);
  ay += __shfl_xor(ay, 32);
  if (half == 0) {
    unsigned int o = (unsigned int)f2bf(ax) | ((unsigned int)f2bf(ay) << 16);
    *(unsigned int*)(h0 + (size_t)n * 64 + c * 2) = o;
  }
}

// ---- aggregation layer 1 (R12-proven masked unroll-8): wave per node,
// lane = 2 channels; et1 in LDS.
__global__ __launch_bounds__(256) void k_agg1(
    const unsigned short* __restrict__ x1, const float* __restrict__ et1,
    const int* __restrict__ offs, const int* __restrict__ cnts,
    const unsigned int* __restrict__ csr1, unsigned short* __restrict__ h1) {
  __shared__ float etl[2048];      // 16 rows x 128 ch, 8 KB
  int t = threadIdx.x;
#pragma unroll
  for (int k = 0; k < 8; ++k) etl[k * 256 + t] = et1[k * 256 + t];
  __syncthreads();
  int lane = t & 63;
  int n = __builtin_amdgcn_readfirstlane(blockIdx.x * 4 + (t >> 6));
  if (n >= NN) return;
  int s = offs[n], e = s + cnts[n];
  const char* xb = (const char*)x1;
  unsigned int voff = (unsigned int)lane * 4u;
  const char* etb = (const char*)etl + (size_t)lane * 8u;
  unsigned int xv = *(const unsigned int*)(xb + ((size_t)(unsigned)n << 8) + voff);
  float ax = bf2f((unsigned short)(xv & 0xFFFF));
  float ay = bf2f((unsigned short)(xv >> 16));
  for (int i = s; i < e; i += 8) {
    unsigned int q0 = csr1[i + 0], q1 = csr1[i + 1], q2 = csr1[i + 2], q3 = csr1[i + 3];
    unsigned int q4 = csr1[i + 4], q5 = csr1[i + 5], q6 = csr1[i + 6], q7 = csr1[i + 7];
    float m1 = (i + 1 < e) ? 1.f : 0.f, m2 = (i + 2 < e) ? 1.f : 0.f;
    float m3 = (i + 3 < e) ? 1.f : 0.f, m4 = (i + 4 < e) ? 1.f : 0.f;
    float m5 = (i + 5 < e) ? 1.f : 0.f, m6 = (i + 6 < e) ? 1.f : 0.f;
    float m7 = (i + 7 < e) ? 1.f : 0.f;
    unsigned int v0 = *(const unsigned int*)(xb + (q0 & 0xFFFFFF00u) + voff);
    unsigned int v1 = *(const unsigned int*)(xb + (q1 & 0xFFFFFF00u) + voff);
    unsigned int v2 = *(const unsigned int*)(xb + (q2 & 0xFFFFFF00u) + voff);
    unsigned int v3 = *(const unsigned int*)(xb + (q3 & 0xFFFFFF00u) + voff);
    unsigned int v4 = *(const unsigned int*)(xb + (q4 & 0xFFFFFF00u) + voff);
    unsigned int v5 = *(const unsigned int*)(xb + (q5 & 0xFFFFFF00u) + voff);
    unsigned int v6 = *(const unsigned int*)(xb + (q6 & 0xFFFFFF00u) + voff);
    unsigned int v7 = *(const unsigned int*)(xb + (q7 & 0xFFFFFF00u) + voff);
    float2 e0 = *(const float2*)(etb + ((q0 & 15u) << 9));
    float2 e1 = *(const float2*)(etb + ((q1 & 15u) << 9));
    float2 e2 = *(const float2*)(etb + ((q2 & 15u) << 9));
    float2 e3 = *(const float2*)(etb + ((q3 & 15u) << 9));
    float2 e4 = *(const float2*)(etb + ((q4 & 15u) << 9));
    float2 e5 = *(const float2*)(etb + ((q5 & 15u) << 9));
    float2 e6 = *(const float2*)(etb + ((q6 & 15u) << 9));
    float2 e7 = *(const float2*)(etb + ((q7 & 15u) << 9));
    float mx, my;
    mx = bf2f((unsigned short)(v0 & 0xFFFF)) + e0.x; my = bf2f((unsigned short)(v0 >> 16)) + e0.y;
    ax += fmaxf(mx, 0.f); ay += fmaxf(my, 0.f);
    mx = bf2f((unsigned short)(v1 & 0xFFFF)) + e1.x; my = bf2f((unsigned short)(v1 >> 16)) + e1.y;
    ax = fmaf(m1, fmaxf(mx, 0.f), ax); ay = fmaf(m1, fmaxf(my, 0.f), ay);
    mx = bf2f((unsigned short)(v2 & 0xFFFF)) + e2.x; my = bf2f((unsigned short)(v2 >> 16)) + e2.y;
    ax = fmaf(m2, fmaxf(mx, 0.f), ax); ay = fmaf(m2, fmaxf(my, 0.f), ay);
    mx = bf2f((unsigned short)(v3 & 0xFFFF)) + e3.x; my = bf2f((unsigned short)(v3 >> 16)) + e3.y;
    ax = fmaf(m3, fmaxf(mx, 0.f), ax); ay = fmaf(m3, fmaxf(my, 0.f), ay);
    mx = bf2f((unsigned short)(v4 & 0xFFFF)) + e4.x; my = bf2f((unsigned short)(v4 >> 16)) + e4.y;
    ax = fmaf(m4, fmaxf(mx, 0.f), ax); ay = fmaf(m4, fmaxf(my, 0.f), ay);
    mx = bf2f((unsigned short)(v5 & 0xFFFF)) + e5.x; my = bf2f((unsigned short)(v5 >> 16)) + e5.y;
    ax = fmaf(m5, fmaxf(mx, 0.f), ax); ay = fmaf(m5, fmaxf(my, 0.f), ay);
    mx = bf2f((unsigned short)(v6 & 0xFFFF)) + e6.x; my = bf2f((unsigned short)(v6 >> 16)) + e6.y;
    ax = fmaf(m6, fmaxf(mx, 0.f), ax); ay = fmaf(m6, fmaxf(my, 0.f), ay);
    mx = bf2f((unsigned short)(v7 & 0xFFFF)) + e7.x; my = bf2f((unsigned short)(v7 >> 16)) + e7.y;
    ax = fmaf(m7, fmaxf(mx, 0.f), ax); ay = fmaf(m7, fmaxf(my, 0.f), ay);
  }
  unsigned int o = (unsigned int)f2bf(ax) | ((unsigned int)f2bf(ay) << 16);
  *(unsigned int*)(h1 + (size_t)n * 128 + lane * 2) = o;
}

// ---- double-GEMM MLP: 128 rows/block (2 tiles), w2 in LDS, one barrier,
// wave-private tls, coalesced dwordx4 stores.
template <int K1>
__global__ __launch_bounds__(256) void k_mlp_t(
    const unsigned short* __restrict__ in,
    const unsigned short* __restrict__ w1z, const float* __restrict__ b1,
    const unsigned short* __restrict__ w2z, const float* __restrict__ b2,
    unsigned short* __restrict__ outb, int N) {
  __shared__ unsigned short tls[4][16][136];   // wave-private mid/out tile
  __shared__ unsigned short b2s[16384];        // 32 KB staged w2 frags
  int t = threadIdx.x;
  int lane = t & 63;
  int wave = t >> 6;
  int rlo = lane & 15, quad = lane >> 4;

#pragma unroll
  for (int k = 0; k < 8; ++k)
    *(shortx8*)&b2s[(k * 256 + t) * 8] = *(const shortx8*)&w2z[(k * 256 + t) * 8];

  float bm1[8], bm2[8];
#pragma unroll
  for (int ct = 0; ct < 8; ++ct) { bm1[ct] = b1[ct * 16 + rlo]; bm2[ct] = b2[ct * 16 + rlo]; }

  __syncthreads();   // b2s ready (only barrier)

#pragma unroll
  for (int t2 = 0; t2 < 2; ++t2) {
    int row0 = blockIdx.x * 128 + t2 * 64 + wave * 16;
    int arow = row0 + rlo;

    floatx4 acc[8];
#pragma unroll
    for (int ct = 0; ct < 8; ++ct) { acc[ct][0]=0.f; acc[ct][1]=0.f; acc[ct][2]=0.f; acc[ct][3]=0.f; }
    const int NS = K1 >> 5;
#pragma unroll
    for (int s = 0; s < NS; ++s) {
      shortx8 a = {0,0,0,0,0,0,0,0};
      if (arow < N) a = *(const shortx8*)(in + (size_t)arow * K1 + s * 32 + quad * 8);
      const unsigned short* wp = w1z + ((size_t)(s * 8) * 64 + lane) * 8;
#pragma unroll
      for (int ct = 0; ct < 8; ++ct) {
        shortx8 b = *(const shortx8*)(wp + ct * 512);
        acc[ct] = __builtin_amdgcn_mfma_f32_16x16x32_bf16(a, b, acc[ct], 0, 0, 0);
      }
    }
#pragma unroll
    for (int ct = 0; ct < 8; ++ct) {
#pragma unroll
      for (int r = 0; r < 4; ++r) {
        float v = elu_fast(acc[ct][r] + bm1[ct]);
        tls[wave][quad * 4 + r][ct * 16 + rlo] = f2bf(v);
      }
    }
    // no barrier: tls[wave] is wave-private; DS ops are wave-ordered.

    floatx4 acc2[8];
#pragma unroll
    for (int ct = 0; ct < 8; ++ct) { acc2[ct][0]=0.f; acc2[ct][1]=0.f; acc2[ct][2]=0.f; acc2[ct][3]=0.f; }
#pragma unroll
    for (int s = 0; s < 4; ++s) {
      shortx8 a = *(const shortx8*)&tls[wave][rlo][s * 32 + quad * 8];
      const unsigned short* wp = &b2s[((s * 8) * 64 + lane) * 8];
#pragma unroll
      for (int ct = 0; ct < 8; ++ct) {
        shortx8 b = *(const shortx8*)(wp + ct * 512);
        acc2[ct] = __builtin_amdgcn_mfma_f32_16x16x32_bf16(a, b, acc2[ct], 0, 0, 0);
      }
    }
#pragma unroll
    for (int ct = 0; ct < 8; ++ct) {
#pragma unroll
      for (int r = 0; r < 4; ++r) {
        float v = elu_fast(acc2[ct][r] + bm2[ct]);
        tls[wave][quad * 4 + r][ct * 16 + rlo] = f2bf(v);
      }
    }
    int srow = lane >> 2;           // 0..15
    int schunk = lane & 3;          // 0..3
    int grow = row0 + srow;
#pragma unroll
    for (int k = 0; k < 4; ++k) {
      int ch = schunk + k * 4;      // 16B chunk (8 cols)
      if (grow < N)
        *(shortx8*)(outb + (size_t)grow * 128 + ch * 8) =
            *(const shortx8*)&tls[wave][srow][ch * 8];
    }
  }
}

// ---- pooling (R7-proven): wave per 32-node chunk, lane = 2 channels.
__global__ __launch_bounds__(256) void k_pool(
    const unsigned short* __restrict__ x2, const int* __restrict__ batch,
    float* __restrict__ hgf) {
  int gt = blockIdx.x * 256 + threadIdx.x;
  int chunk = gt >> 6, lane = gt & 63;
  int n0 = chunk * 32;
  if (n0 >= NN) return;
  int nend = n0 + 32; if (nend > NN) nend = NN;
  float ax = 0.f, ay = 0.f;
  const unsigned short* xp = x2 + lane * 2;
  int gcur = batch[n0];
  for (int n = n0; n < nend; ++n) {
    int g = batch[n];
    if (g != gcur) {
      atomicAdd(&hgf[gcur * 128 + lane * 2], ax);
      atomicAdd(&hgf[gcur * 128 + lane * 2 + 1], ay);
      ax = 0.f; ay = 0.f; gcur = g;
    }
    unsigned int v = *(const unsigned int*)(xp + (size_t)n * 128);
    ax += bf2f((unsigned short)(v & 0xFFFF));
    ay += bf2f((unsigned short)(v >> 16));
  }
  atomicAdd(&hgf[gcur * 128 + lane * 2], ax);
  atomicAdd(&hgf[gcur * 128 + lane * 2 + 1], ay);
}

// ---- head MLP: A rows fp32 (pooled), out fp32 = (relu(in@l1+b))@l2+b
__global__ void k_head(const float* __restrict__ in,
                       const unsigned short* __restrict__ w1z, const float* __restrict__ b1,
                       const unsigned short* __restrict__ w2z, const float* __restrict__ b2,
                       float* __restrict__ outf, int N) {
  __shared__ unsigned short tls[4][16][136];
  int lane = threadIdx.x & 63;
  int wave = threadIdx.x >> 6;
  int row0 = blockIdx.x * 64 + wave * 16;
  int rlo = lane & 15, quad = lane >> 4;
  int arow = row0 + rlo;
  floatx4 acc[8];
#pragma unroll
  for (int ct = 0; ct < 8; ++ct) { acc[ct][0]=0.f; acc[ct][1]=0.f; acc[ct][2]=0.f; acc[ct][3]=0.f; }
#pragma unroll
  for (int s = 0; s < 4; ++s) {
    shortx8 a = {0,0,0,0,0,0,0,0};
    if (arow < N) {
      const float* rp = in + (size_t)arow * 128 + s * 32 + quad * 8;
      float4 f0 = *(const float4*)rp;
      float4 f1 = *(const float4*)(rp + 4);
      a[0] = (short)f2bf(f0.x); a[1] = (short)f2bf(f0.y);
      a[2] = (short)f2bf(f0.z); a[3] = (short)f2bf(f0.w);
      a[4] = (short)f2bf(f1.x); a[5] = (short)f2bf(f1.y);
      a[6] = (short)f2bf(f1.z); a[7] = (short)f2bf(f1.w);
    }
    const unsigned short* wp = w1z + ((size_t)(s * 8) * 64 + lane) * 8;
#pragma unroll
    for (int ct = 0; ct < 8; ++ct) {
      shortx8 b = *(const shortx8*)(wp + ct * 512);
      acc[ct] = __builtin_amdgcn_mfma_f32_16x16x32_bf16(a, b, acc[ct], 0, 0, 0);
    }
  }
#pragma unroll
  for (int ct = 0; ct < 8; ++ct) {
    float bm = b1[ct * 16 + rlo];
#pragma unroll
    for (int r = 0; r < 4; ++r) {
      float v = acc[ct][r] + bm;
      v = v > 0.f ? v : 0.f;  // relu
      tls[wave][quad * 4 + r][ct * 16 + rlo] = f2bf(v);
    }
  }
  __syncthreads();
  floatx4 acc2[8];
#pragma unroll
  for (int ct = 0; ct < 8; ++ct) { acc2[ct][0]=0.f; acc2[ct][1]=0.f; acc2[ct][2]=0.f; acc2[ct][3]=0.f; }
#pragma unroll
  for (int s = 0; s < 4; ++s) {
    shortx8 a = *(const shortx8*)&tls[wave][rlo][s * 32 + quad * 8];
    const unsigned short* wp = w2z + ((size_t)(s * 8) * 64 + lane) * 8;
#pragma unroll
    for (int ct = 0; ct < 8; ++ct) {
      shortx8 b = *(const shortx8*)(wp + ct * 512);
      acc2[ct] = __builtin_amdgcn_mfma_f32_16x16x32_bf16(a, b, acc2[ct], 0, 0, 0);
    }
  }
#pragma unroll
  for (int ct = 0; ct < 8; ++ct) {
    float bm = b2[ct * 16 + rlo];
#pragma unroll
    for (int r = 0; r < 4; ++r) {
      int rr = row0 + quad * 4 + r;
      if (rr < N) outf[(size_t)rr * 128 + ct * 16 + rlo] = acc2[ct][r] + bm;
    }
  }
}

extern "C" void kernel_launch(void* const* d_in, const int* in_sizes, int n_in,
                              void* d_out, int out_size, void* d_ws, size_t ws_size,
                              hipStream_t stream) {
  const int* x_idx  = (const int*)d_in[0];
  const int* e_src  = (const int*)d_in[1];
  const int* e_dst  = e_src + NE;
  const int* e_attr = (const int*)d_in[2];
  const int* batch  = (const int*)d_in[3];
  const float* atom = (const float*)d_in[4];
  const float* bond = (const float*)d_in[5];
  const float* we0  = (const float*)d_in[6];
  const float* be0  = (const float*)d_in[7];
  const float* w1_0 = (const float*)d_in[8];
  const float* b1_0 = (const float*)d_in[9];
  const float* w2_0 = (const float*)d_in[10];
  const float* b2_0 = (const float*)d_in[11];
  const float* we1  = (const float*)d_in[12];
  const float* be1  = (const float*)d_in[13];
  const float* w1_1 = (const float*)d_in[14];
  const float* b1_1 = (const float*)d_in[15];
  const float* w2_1 = (const float*)d_in[16];
  const float* b2_1 = (const float*)d_in[17];
  const float* l1w  = (const float*)d_in[18];
  const float* l1b  = (const float*)d_in[19];
  const float* l2w  = (const float*)d_in[20];
  const float* l2b  = (const float*)d_in[21];

  char* ws = (char*)d_ws;
  size_t off = 0;
  auto alloc = [&](size_t bytes) -> void* {
    void* p = ws + off;
    off = (off + bytes + 255) & ~(size_t)255;
    return p;
  };
  int* bcursor = (int*)alloc((size_t)NB * 4);
  int* offs    = (int*)alloc((size_t)NN * 4);
  int* cnts    = (int*)alloc((size_t)NN * 4);
  float* et1   = (float*)alloc(16 * 128 * 4);
  unsigned short* M0 = (unsigned short*)alloc((size_t)1904 * 64 * 2);  // bf16
  float* hgf   = (float*)alloc((size_t)NG * 128 * 4);
  unsigned short* w1_0z = (unsigned short*)alloc(64 * 128 * 2);
  unsigned short* w2_0z = (unsigned short*)alloc(128 * 128 * 2);
  unsigned short* w1_1z = (unsigned short*)alloc(128 * 128 * 2);
  unsigned short* w2_1z = (unsigned short*)alloc(128 * 128 * 2);
  unsigned short* l1z   = (unsigned short*)alloc(128 * 128 * 2);
  unsigned short* l2z   = (unsigned short*)alloc(128 * 128 * 2);
  uint2* pairs = (uint2*)alloc((size_t)NB * PS * 8);       // dead after k_fine
  unsigned int* csr0 = (unsigned int*)alloc((size_t)NB * CS * 4);
  unsigned int* csr1 = (unsigned int*)alloc((size_t)NB * CS * 4);
  unsigned short* x1 = (unsigned short*)alloc((size_t)NN * 128 * 2);
  unsigned short* h1 = (unsigned short*)alloc((size_t)NN * 128 * 2);
  unsigned short* h0 = (unsigned short*)pairs;  // 12.8 MB alias: pairs dead before agg0
  unsigned short* x2 = h1;  // in-place mlp1 (wave reads own rows before writing)

  k_prep<<<885, 256, 0, stream>>>(bond, we0, be0, we1, be1, atom, et1, M0, hgf, bcursor,
                                  w1_0, w2_0, w1_1, w2_1, l1w, l2w,
                                  w1_0z, w2_0z, w1_1z, w2_1z, l1z, l2z);
  k_bin<<<(NE + 4095) / 4096, 256, 0, stream>>>(e_src, e_dst, e_attr, x_idx, bcursor, pairs);
  k_fine<<<NB, 256, 0, stream>>>(pairs, bcursor, offs, cnts, csr0, csr1);
  k_agg0<<<NN / 4, 256, 0, stream>>>(x_idx, atom, M0, offs, cnts, csr0, h0);
  k_mlp_t<64><<<(NN + 127) / 128, 256, 0, stream>>>(h0, w1_0z, b1_0, w2_0z, b2_0, x1, NN);
  k_agg1<<<NN / 4, 256, 0, stream>>>(x1, et1, offs, cnts, csr1, h1);
  k_mlp_t<128><<<(NN + 127) / 128, 256, 0, stream>>>(h1, w1_1z, b1_1, w2_1z, b2_1, x2, NN);
  k_pool<<<(((NN + 31) / 32) * 64 + 255) / 256, 256, 0, stream>>>(x2, batch, hgf);
  k_head<<<(NG + 63) / 64, 256, 0, stream>>>(hgf, l1z, l1b, l2z, l2b, (float*)d_out, NG);
}

// Round 15
// 323.134 us; speedup vs baseline: 1.0233x; 1.0087x over previous
//
#include <hip/hip_runtime.h>
#include <hip/hip_bf16.h>

// GINE on MI355X — fp32 inputs/outputs; bf16 MFMA internals.
static const int NN = 100000;   // nodes
static const int NE = 1600000;  // edges
static const int NG = 512;      // graphs
static const int NB = 391;      // coarse buckets of 256 nodes (dst >> 8)
static const int PS = 4608;     // pairs region per bucket (mean 4096 + 8 sigma)
static const int CS = 4624;     // csr region per bucket (PS + 16 zero-fill slack)

typedef __attribute__((ext_vector_type(8))) short shortx8;
typedef __attribute__((ext_vector_type(4))) float floatx4;
typedef __attribute__((ext_vector_type(2))) float floatx2;

__device__ __forceinline__ float bf2f(unsigned short u) {
  union { unsigned int i; float f; } v; v.i = ((unsigned int)u) << 16; return v.f;
}
__device__ __forceinline__ unsigned short f2bf(float f) {
  union { float f; unsigned int i; } v; v.f = f;
  return (unsigned short)((v.i + 0x7FFFu + ((v.i >> 16) & 1u)) >> 16);
}
__device__ __forceinline__ float elu_fast(float v) {
  return v > 0.f ? v : (__builtin_amdgcn_exp2f(v * 1.44269504f) - 1.f);
}
// unpack packed 2x bf16 -> float2 (2 VALU: shl, and)
__device__ __forceinline__ floatx2 unpk(unsigned int v) {
  union { unsigned int i; float f; } a, b;
  a.i = v << 16; b.i = v & 0xFFFF0000u;
  floatx2 r; r.x = a.f; r.y = b.f; return r;
}

// ---- one prep kernel ----------------------------------------------------
// blocks 0..7: et1 | 8..483: M0 (bf16) | 484..867: weight swizzle |
// 868..883: zero hgf | 884: bcursor init.
__global__ void k_prep(const float* __restrict__ bond,
                       const float* __restrict__ we0, const float* __restrict__ be0,
                       const float* __restrict__ we1, const float* __restrict__ be1,
                       const float* __restrict__ atom,
                       float* __restrict__ et1, unsigned short* __restrict__ M0,
                       float* __restrict__ hgf, int* __restrict__ bcursor,
                       const float* __restrict__ s0, const float* __restrict__ s1,
                       const float* __restrict__ s2, const float* __restrict__ s3,
                       const float* __restrict__ s4, const float* __restrict__ s5,
                       unsigned short* __restrict__ d0, unsigned short* __restrict__ d1,
                       unsigned short* __restrict__ d2, unsigned short* __restrict__ d3,
                       unsigned short* __restrict__ d4, unsigned short* __restrict__ d5) {
  int blk = blockIdx.x, t = threadIdx.x;
  if (blk < 8) {                      // et1[16][128] = bond@we1 + be1
    int i = blk * 256 + t;
    int b = i >> 7, c = i & 127;
    float acc = be1[c];
    for (int k = 0; k < 64; ++k) acc += bond[b * 64 + k] * we1[k * 128 + c];
    et1[i] = acc;
  } else if (blk < 484) {             // M0 (bf16) = relu(atom + bond@we0 + be0)
    int i = (blk - 8) * 256 + t;      // 476*256 == 119*16*64
    int c = i & 63, b = (i >> 6) & 15, a = i >> 10;
    float acc = be0[c];
    for (int k = 0; k < 64; ++k) acc += bond[b * 64 + k] * we0[k * 64 + c];
    acc += atom[a * 64 + c];
    M0[i] = f2bf(acc > 0.f ? acc : 0.f);
  } else if (blk < 868) {             // weight swizzle into MFMA B-frag order
    int task = (blk - 484) >> 6;
    int i = ((blk - 484) & 63) * 256 + t;
    const float* w; unsigned short* wz; int K;
    switch (task) {
      case 0: w = s0; wz = d0; K = 64; break;
      case 1: w = s1; wz = d1; K = 128; break;
      case 2: w = s2; wz = d2; K = 128; break;
      case 3: w = s3; wz = d3; K = 128; break;
      case 4: w = s4; wz = d4; K = 128; break;
      default: w = s5; wz = d5; K = 128; break;
    }
    if (i >= K * 128) return;
    int j = i & 7, lane = (i >> 3) & 63, ct = (i >> 9) & 7, s = i >> 12;
    int k = s * 32 + (lane >> 4) * 8 + j;
    int m = ct * 16 + (lane & 15);
    wz[i] = f2bf(w[k * 128 + m]);
  } else if (blk < 884) {             // zero hgf (512*128 floats)
    int base = (blk - 868) * 4096;
#pragma unroll
    for (int k = 0; k < 16; ++k) hgf[base + k * 256 + t] = 0.f;
  } else {                            // bcursor fixed bases
    if (t < NB) bcursor[t] = t * PS;
    int u = t + 256;
    if (u < NB) bcursor[u] = u * PS;
  }
}

// Pass B: bin 4096-edge chunks by coarse bucket into fixed per-bucket regions.
__global__ void k_bin(const int* __restrict__ src, const int* __restrict__ dstp,
                      const int* __restrict__ ea, const int* __restrict__ x_idx,
                      int* __restrict__ bcursor, uint2* __restrict__ pairs) {
  __shared__ int cnt[512];
  __shared__ int incl[512];
  __shared__ int cur[NB];
  __shared__ int rbase[NB];
  __shared__ uint2 stage[4096];
  int t = threadIdx.x;
  int e0 = blockIdx.x * 4096;
  int ecnt = NE - e0; if (ecnt > 4096) ecnt = 4096;
  cnt[t] = 0; cnt[t + 256] = 0;
  __syncthreads();
  for (int k = 0; k < 16; ++k) {
    int i = k * 256 + t;
    if (i < ecnt) atomicAdd(&cnt[dstp[e0 + i] >> 8], 1);
  }
  __syncthreads();
  incl[t] = cnt[t]; incl[t + 256] = cnt[t + 256];
  __syncthreads();
  for (int d = 1; d < 512; d <<= 1) {
    int v0 = (t >= d) ? incl[t - d] : 0;
    int v1 = (t + 256 >= d) ? incl[t + 256 - d] : 0;
    __syncthreads();
    incl[t] += v0; incl[t + 256] += v1;
    __syncthreads();
  }
  if (t < NB) { cur[t] = incl[t] - cnt[t]; if (cnt[t]) rbase[t] = atomicAdd(&bcursor[t], cnt[t]); }
  int u = t + 256;
  if (u < NB) { cur[u] = incl[u] - cnt[u]; if (cnt[u]) rbase[u] = atomicAdd(&bcursor[u], cnt[u]); }
  __syncthreads();
  for (int k = 0; k < 16; ++k) {
    int i = k * 256 + t;
    if (i < ecnt) {
      int e = e0 + i;
      int d = dstp[e];
      int s = src[e];
      unsigned int pk = (unsigned int)s | ((unsigned int)(x_idx[s] * 16 + ea[e]) << 17);
      int p = atomicAdd(&cur[d >> 8], 1);
      stage[p] = make_uint2((unsigned int)d, pk);
    }
  }
  __syncthreads();
  for (int j = t; j < ecnt; j += 256) {   // bucket from dst — no search
    uint2 p = stage[j];
    int b = (int)(p.x >> 8);
    int excl = incl[b] - cnt[b];
    pairs[rbase[b] + (j - excl)] = p;
  }
}

// Pass C: fine counting-sort per bucket; absolute offs + cnts; 16 zero slots.
//   csr0[i] = M0-row byte offset (bf16 rows: idx17*128)
//   csr1[i] = (src*256) | bond
__global__ void k_fine(const uint2* __restrict__ pairs, const int* __restrict__ bcursor,
                       int* __restrict__ offs, int* __restrict__ cnts,
                       unsigned int* __restrict__ csr0, unsigned int* __restrict__ csr1) {
  __shared__ int cnt[256];
  __shared__ int incl[256];
  __shared__ int cur[256];
  int b = blockIdx.x;
  int t = threadIdx.x;
  int start = b * PS;
  int endv = bcursor[b];
  int cbase = b * CS;
  int base_n = b << 8;
  cnt[t] = 0;
  __syncthreads();
  for (int j = start + t; j < endv; j += 256)
    atomicAdd(&cnt[(int)pairs[j].x - base_n], 1);
  __syncthreads();
  incl[t] = cnt[t];
  __syncthreads();
  for (int d = 1; d < 256; d <<= 1) {
    int v = (t >= d) ? incl[t - d] : 0;
    __syncthreads();
    incl[t] += v;
    __syncthreads();
  }
  int excl = incl[t] - cnt[t];
  cur[t] = excl;
  int node = base_n + t;
  if (node < NN) { offs[node] = cbase + excl; cnts[node] = cnt[t]; }
  __syncthreads();
  for (int j = start + t; j < endv; j += 256) {
    uint2 p = pairs[j];
    int pos = cbase + atomicAdd(&cur[(int)p.x - base_n], 1);
    unsigned int pk = p.y;
    unsigned int idx17 = pk >> 17;
    csr0[pos] = idx17 << 7;                 // bf16 M0 rows: 128 B
    csr1[pos] = ((pk & 0x1FFFFu) << 8) | (idx17 & 15u);
  }
  __syncthreads();
  int total = incl[255];
  if (t < 16) { csr0[cbase + total + t] = 0u; csr1[cbase + total + t] = 0u; }
}

// ---- aggregation layer 0: wave per node; bf16 M0, two edges per gather
// instruction; packed-f32 accumulate; shfl_xor(32) merge.
__global__ __launch_bounds__(256) void k_agg0(
    const int* __restrict__ x_idx, const float* __restrict__ atom,
    const unsigned short* __restrict__ M0, const int* __restrict__ offs,
    const int* __restrict__ cnts,
    const unsigned int* __restrict__ csr0, unsigned short* __restrict__ h0) {
  int t = threadIdx.x, lane = t & 63;
  int half = lane >> 5, c = lane & 31;
  int n = __builtin_amdgcn_readfirstlane(blockIdx.x * 4 + (t >> 6));
  if (n >= NN) return;
  int s = offs[n], e = s + cnts[n];
  const char* Mb = (const char*)M0;
  unsigned int voff = (unsigned int)c * 4u;
  floatx2 acc; acc.x = 0.f; acc.y = 0.f;
  if (half == 0) {   // self term: h = x + agg
    float2 sv = *(const float2*)((const char*)atom +
                                 ((size_t)(unsigned)x_idx[n] << 8) + (size_t)c * 8u);
    acc.x = sv.x; acc.y = sv.y;
  }
  for (int i = s; i < e; i += 16) {
    unsigned int a0 = csr0[i + 0],  b0 = csr0[i + 1];
    unsigned int a1 = csr0[i + 2],  b1 = csr0[i + 3];
    unsigned int a2 = csr0[i + 4],  b2 = csr0[i + 5];
    unsigned int a3 = csr0[i + 6],  b3 = csr0[i + 7];
    unsigned int a4 = csr0[i + 8],  b4 = csr0[i + 9];
    unsigned int a5 = csr0[i + 10], b5 = csr0[i + 11];
    unsigned int a6 = csr0[i + 12], b6 = csr0[i + 13];
    unsigned int a7 = csr0[i + 14], b7 = csr0[i + 15];
    unsigned int q0 = half ? b0 : a0, q1 = half ? b1 : a1;
    unsigned int q2 = half ? b2 : a2, q3 = half ? b3 : a3;
    unsigned int q4 = half ? b4 : a4, q5 = half ? b5 : a5;
    unsigned int q6 = half ? b6 : a6, q7 = half ? b7 : a7;
    floatx2 m0, m1, m2, m3, m4, m5, m6, m7;
    m0.x = m0.y = (i + 0 + half < e) ? 1.f : 0.f;
    m1.x = m1.y = (i + 2 + half < e) ? 1.f : 0.f;
    m2.x = m2.y = (i + 4 + half < e) ? 1.f : 0.f;
    m3.x = m3.y = (i + 6 + half < e) ? 1.f : 0.f;
    m4.x = m4.y = (i + 8 + half < e) ? 1.f : 0.f;
    m5.x = m5.y = (i + 10 + half < e) ? 1.f : 0.f;
    m6.x = m6.y = (i + 12 + half < e) ? 1.f : 0.f;
    m7.x = m7.y = (i + 14 + half < e) ? 1.f : 0.f;
    unsigned int v0 = *(const unsigned int*)(Mb + q0 + voff);
    unsigned int v1 = *(const unsigned int*)(Mb + q1 + voff);
    unsigned int v2 = *(const unsigned int*)(Mb + q2 + voff);
    unsigned int v3 = *(const unsigned int*)(Mb + q3 + voff);
    unsigned int v4 = *(const unsigned int*)(Mb + q4 + voff);
    unsigned int v5 = *(const unsigned int*)(Mb + q5 + voff);
    unsigned int v6 = *(const unsigned int*)(Mb + q6 + voff);
    unsigned int v7 = *(const unsigned int*)(Mb + q7 + voff);
    acc = __builtin_elementwise_fma(m0, unpk(v0), acc);
    acc = __builtin_elementwise_fma(m1, unpk(v1), acc);
    acc = __builtin_elementwise_fma(m2, unpk(v2), acc);
    acc = __builtin_elementwise_fma(m3, unpk(v3), acc);
    acc = __builtin_elementwise_fma(m4, unpk(v4), acc);
    acc = __builtin_elementwise_fma(m5, unpk(v5), acc);
    acc = __builtin_elementwise_fma(m6, unpk(v6), acc);
    acc = __builtin_elementwise_fma(m7, unpk(v7), acc);
  }
  float ax = acc.x + __shfl_xor(acc.x, 32);
  float ay = acc.y + __shfl_xor(acc.y, 32);
  if (half == 0) {
    unsigned int o = (unsigned int)f2bf(ax) | ((unsigned int)f2bf(ay) << 16);
    *(unsigned int*)(h0 + (size_t)n * 64 + c * 2) = o;
  }
}

// ---- aggregation layer 1: wave per node, lane = 2 channels; et1 in LDS;
// masked unroll-8 with packed-f32 math (pk_add/pk_max/pk_fma).
__global__ __launch_bounds__(256) void k_agg1(
    const unsigned short* __restrict__ x1, const float* __restrict__ et1,
    const int* __restrict__ offs, const int* __restrict__ cnts,
    const unsigned int* __restrict__ csr1, unsigned short* __restrict__ h1) {
  __shared__ float etl[2048];      // 16 rows x 128 ch, 8 KB
  int t = threadIdx.x;
#pragma unroll
  for (int k = 0; k < 8; ++k) etl[k * 256 + t] = et1[k * 256 + t];
  __syncthreads();
  int lane = t & 63;
  int n = __builtin_amdgcn_readfirstlane(blockIdx.x * 4 + (t >> 6));
  if (n >= NN) return;
  int s = offs[n], e = s + cnts[n];
  const char* xb = (const char*)x1;
  unsigned int voff = (unsigned int)lane * 4u;
  const char* etb = (const char*)etl + (size_t)lane * 8u;
  unsigned int xv = *(const unsigned int*)(xb + ((size_t)(unsigned)n << 8) + voff);
  floatx2 acc = unpk(xv);
  floatx2 zero2; zero2.x = 0.f; zero2.y = 0.f;
  for (int i = s; i < e; i += 8) {
    unsigned int q0 = csr1[i + 0], q1 = csr1[i + 1], q2 = csr1[i + 2], q3 = csr1[i + 3];
    unsigned int q4 = csr1[i + 4], q5 = csr1[i + 5], q6 = csr1[i + 6], q7 = csr1[i + 7];
    floatx2 k1, k2, k3, k4, k5, k6, k7;
    k1.x = k1.y = (i + 1 < e) ? 1.f : 0.f;
    k2.x = k2.y = (i + 2 < e) ? 1.f : 0.f;
    k3.x = k3.y = (i + 3 < e) ? 1.f : 0.f;
    k4.x = k4.y = (i + 4 < e) ? 1.f : 0.f;
    k5.x = k5.y = (i + 5 < e) ? 1.f : 0.f;
    k6.x = k6.y = (i + 6 < e) ? 1.f : 0.f;
    k7.x = k7.y = (i + 7 < e) ? 1.f : 0.f;
    unsigned int v0 = *(const unsigned int*)(xb + (q0 & 0xFFFFFF00u) + voff);
    unsigned int v1 = *(const unsigned int*)(xb + (q1 & 0xFFFFFF00u) + voff);
    unsigned int v2 = *(const unsigned int*)(xb + (q2 & 0xFFFFFF00u) + voff);
    unsigned int v3 = *(const unsigned int*)(xb + (q3 & 0xFFFFFF00u) + voff);
    unsigned int v4 = *(const unsigned int*)(xb + (q4 & 0xFFFFFF00u) + voff);
    unsigned int v5 = *(const unsigned int*)(xb + (q5 & 0xFFFFFF00u) + voff);
    unsigned int v6 = *(const unsigned int*)(xb + (q6 & 0xFFFFFF00u) + voff);
    unsigned int v7 = *(const unsigned int*)(xb + (q7 & 0xFFFFFF00u) + voff);
    floatx2 e0 = *(const floatx2*)(etb + ((q0 & 15u) << 9));
    floatx2 e1 = *(const floatx2*)(etb + ((q1 & 15u) << 9));
    floatx2 e2 = *(const floatx2*)(etb + ((q2 & 15u) << 9));
    floatx2 e3 = *(const floatx2*)(etb + ((q3 & 15u) << 9));
    floatx2 e4 = *(const floatx2*)(etb + ((q4 & 15u) << 9));
    floatx2 e5 = *(const floatx2*)(etb + ((q5 & 15u) << 9));
    floatx2 e6 = *(const floatx2*)(etb + ((q6 & 15u) << 9));
    floatx2 e7 = *(const floatx2*)(etb + ((q7 & 15u) << 9));
    acc = acc + __builtin_elementwise_max(unpk(v0) + e0, zero2);
    acc = __builtin_elementwise_fma(k1, __builtin_elementwise_max(unpk(v1) + e1, zero2), acc);
    acc = __builtin_elementwise_fma(k2, __builtin_elementwise_max(unpk(v2) + e2, zero2), acc);
    acc = __builtin_elementwise_fma(k3, __builtin_elementwise_max(unpk(v3) + e3, zero2), acc);
    acc = __builtin_elementwise_fma(k4, __builtin_elementwise_max(unpk(v4) + e4, zero2), acc);
    acc = __builtin_elementwise_fma(k5, __builtin_elementwise_max(unpk(v5) + e5, zero2), acc);
    acc = __builtin_elementwise_fma(k6, __builtin_elementwise_max(unpk(v6) + e6, zero2), acc);
    acc = __builtin_elementwise_fma(k7, __builtin_elementwise_max(unpk(v7) + e7, zero2), acc);
  }
  unsigned int o = (unsigned int)f2bf(acc.x) | ((unsigned int)f2bf(acc.y) << 16);
  *(unsigned int*)(h1 + (size_t)n * 128 + lane * 2) = o;
}

// ---- double-GEMM MLP: 128 rows/block (2 tiles), w2 in LDS, one barrier,
// wave-private tls, coalesced dwordx4 stores.
template <int K1>
__global__ __launch_bounds__(256) void k_mlp_t(
    const unsigned short* __restrict__ in,
    const unsigned short* __restrict__ w1z, const float* __restrict__ b1,
    const unsigned short* __restrict__ w2z, const float* __restrict__ b2,
    unsigned short* __restrict__ outb, int N) {
  __shared__ unsigned short tls[4][16][136];   // wave-private mid/out tile
  __shared__ unsigned short b2s[16384];        // 32 KB staged w2 frags
  int t = threadIdx.x;
  int lane = t & 63;
  int wave = t >> 6;
  int rlo = lane & 15, quad = lane >> 4;

#pragma unroll
  for (int k = 0; k < 8; ++k)
    *(shortx8*)&b2s[(k * 256 + t) * 8] = *(const shortx8*)&w2z[(k * 256 + t) * 8];

  float bm1[8], bm2[8];
#pragma unroll
  for (int ct = 0; ct < 8; ++ct) { bm1[ct] = b1[ct * 16 + rlo]; bm2[ct] = b2[ct * 16 + rlo]; }

  __syncthreads();   // b2s ready (only barrier)

#pragma unroll
  for (int t2 = 0; t2 < 2; ++t2) {
    int row0 = blockIdx.x * 128 + t2 * 64 + wave * 16;
    int arow = row0 + rlo;

    floatx4 acc[8];
#pragma unroll
    for (int ct = 0; ct < 8; ++ct) { acc[ct][0]=0.f; acc[ct][1]=0.f; acc[ct][2]=0.f; acc[ct][3]=0.f; }
    const int NS = K1 >> 5;
#pragma unroll
    for (int s = 0; s < NS; ++s) {
      shortx8 a = {0,0,0,0,0,0,0,0};
      if (arow < N) a = *(const shortx8*)(in + (size_t)arow * K1 + s * 32 + quad * 8);
      const unsigned short* wp = w1z + ((size_t)(s * 8) * 64 + lane) * 8;
#pragma unroll
      for (int ct = 0; ct < 8; ++ct) {
        shortx8 b = *(const shortx8*)(wp + ct * 512);
        acc[ct] = __builtin_amdgcn_mfma_f32_16x16x32_bf16(a, b, acc[ct], 0, 0, 0);
      }
    }
#pragma unroll
    for (int ct = 0; ct < 8; ++ct) {
#pragma unroll
      for (int r = 0; r < 4; ++r) {
        float v = elu_fast(acc[ct][r] + bm1[ct]);
        tls[wave][quad * 4 + r][ct * 16 + rlo] = f2bf(v);
      }
    }
    // no barrier: tls[wave] is wave-private; DS ops are wave-ordered.

    floatx4 acc2[8];
#pragma unroll
    for (int ct = 0; ct < 8; ++ct) { acc2[ct][0]=0.f; acc2[ct][1]=0.f; acc2[ct][2]=0.f; acc2[ct][3]=0.f; }
#pragma unroll
    for (int s = 0; s < 4; ++s) {
      shortx8 a = *(const shortx8*)&tls[wave][rlo][s * 32 + quad * 8];
      const unsigned short* wp = &b2s[((s * 8) * 64 + lane) * 8];
#pragma unroll
      for (int ct = 0; ct < 8; ++ct) {
        shortx8 b = *(const shortx8*)(wp + ct * 512);
        acc2[ct] = __builtin_amdgcn_mfma_f32_16x16x32_bf16(a, b, acc2[ct], 0, 0, 0);
      }
    }
#pragma unroll
    for (int ct = 0; ct < 8; ++ct) {
#pragma unroll
      for (int r = 0; r < 4; ++r) {
        float v = elu_fast(acc2[ct][r] + bm2[ct]);
        tls[wave][quad * 4 + r][ct * 16 + rlo] = f2bf(v);
      }
    }
    int srow = lane >> 2;           // 0..15
    int schunk = lane & 3;          // 0..3
    int grow = row0 + srow;
#pragma unroll
    for (int k = 0; k < 4; ++k) {
      int ch = schunk + k * 4;      // 16B chunk (8 cols)
      if (grow < N)
        *(shortx8*)(outb + (size_t)grow * 128 + ch * 8) =
            *(const shortx8*)&tls[wave][srow][ch * 8];
    }
  }
}

// ---- pooling (R7-proven): wave per 32-node chunk, lane = 2 channels.
__global__ __launch_bounds__(256) void k_pool(
    const unsigned short* __restrict__ x2, const int* __restrict__ batch,
    float* __restrict__ hgf) {
  int gt = blockIdx.x * 256 + threadIdx.x;
  int chunk = gt >> 6, lane = gt & 63;
  int n0 = chunk * 32;
  if (n0 >= NN) return;
  int nend = n0 + 32; if (nend > NN) nend = NN;
  float ax = 0.f, ay = 0.f;
  const unsigned short* xp = x2 + lane * 2;
  int gcur = batch[n0];
  for (int n = n0; n < nend; ++n) {
    int g = batch[n];
    if (g != gcur) {
      atomicAdd(&hgf[gcur * 128 + lane * 2], ax);
      atomicAdd(&hgf[gcur * 128 + lane * 2 + 1], ay);
      ax = 0.f; ay = 0.f; gcur = g;
    }
    unsigned int v = *(const unsigned int*)(xp + (size_t)n * 128);
    ax += bf2f((unsigned short)(v & 0xFFFF));
    ay += bf2f((unsigned short)(v >> 16));
  }
  atomicAdd(&hgf[gcur * 128 + lane * 2], ax);
  atomicAdd(&hgf[gcur * 128 + lane * 2 + 1], ay);
}

// ---- head MLP: A rows fp32 (pooled), out fp32 = (relu(in@l1+b))@l2+b
__global__ void k_head(const float* __restrict__ in,
                       const unsigned short* __restrict__ w1z, const float* __restrict__ b1,
                       const unsigned short* __restrict__ w2z, const float* __restrict__ b2,
                       float* __restrict__ outf, int N) {
  __shared__ unsigned short tls[4][16][136];
  int lane = threadIdx.x & 63;
  int wave = threadIdx.x >> 6;
  int row0 = blockIdx.x * 64 + wave * 16;
  int rlo = lane & 15, quad = lane >> 4;
  int arow = row0 + rlo;
  floatx4 acc[8];
#pragma unroll
  for (int ct = 0; ct < 8; ++ct) { acc[ct][0]=0.f; acc[ct][1]=0.f; acc[ct][2]=0.f; acc[ct][3]=0.f; }
#pragma unroll
  for (int s = 0; s < 4; ++s) {
    shortx8 a = {0,0,0,0,0,0,0,0};
    if (arow < N) {
      const float* rp = in + (size_t)arow * 128 + s * 32 + quad * 8;
      float4 f0 = *(const float4*)rp;
      float4 f1 = *(const float4*)(rp + 4);
      a[0] = (short)f2bf(f0.x); a[1] = (short)f2bf(f0.y);
      a[2] = (short)f2bf(f0.z); a[3] = (short)f2bf(f0.w);
      a[4] = (short)f2bf(f1.x); a[5] = (short)f2bf(f1.y);
      a[6] = (short)f2bf(f1.z); a[7] = (short)f2bf(f1.w);
    }
    const unsigned short* wp = w1z + ((size_t)(s * 8) * 64 + lane) * 8;
#pragma unroll
    for (int ct = 0; ct < 8; ++ct) {
      shortx8 b = *(const shortx8*)(wp + ct * 512);
      acc[ct] = __builtin_amdgcn_mfma_f32_16x16x32_bf16(a, b, acc[ct], 0, 0, 0);
    }
  }
#pragma unroll
  for (int ct = 0; ct < 8; ++ct) {
    float bm = b1[ct * 16 + rlo];
#pragma unroll
    for (int r = 0; r < 4; ++r) {
      float v = acc[ct][r] + bm;
      v = v > 0.f ? v : 0.f;  // relu
      tls[wave][quad * 4 + r][ct * 16 + rlo] = f2bf(v);
    }
  }
  __syncthreads();
  floatx4 acc2[8];
#pragma unroll
  for (int ct = 0; ct < 8; ++ct) { acc2[ct][0]=0.f; acc2[ct][1]=0.f; acc2[ct][2]=0.f; acc2[ct][3]=0.f; }
#pragma unroll
  for (int s = 0; s < 4; ++s) {
    shortx8 a = *(const shortx8*)&tls[wave][rlo][s * 32 + quad * 8];
    const unsigned short* wp = w2z + ((size_t)(s * 8) * 64 + lane) * 8;
#pragma unroll
    for (int ct = 0; ct < 8; ++ct) {
      shortx8 b = *(const shortx8*)(wp + ct * 512);
      acc2[ct] = __builtin_amdgcn_mfma_f32_16x16x32_bf16(a, b, acc2[ct], 0, 0, 0);
    }
  }
#pragma unroll
  for (int ct = 0; ct < 8; ++ct) {
    float bm = b2[ct * 16 + rlo];
#pragma unroll
    for (int r = 0; r < 4; ++r) {
      int rr = row0 + quad * 4 + r;
      if (rr < N) outf[(size_t)rr * 128 + ct * 16 + rlo] = acc2[ct][r] + bm;
    }
  }
}

extern "C" void kernel_launch(void* const* d_in, const int* in_sizes, int n_in,
                              void* d_out, int out_size, void* d_ws, size_t ws_size,
                              hipStream_t stream) {
  const int* x_idx  = (const int*)d_in[0];
  const int* e_src  = (const int*)d_in[1];
  const int* e_dst  = e_src + NE;
  const int* e_attr = (const int*)d_in[2];
  const int* batch  = (const int*)d_in[3];
  const float* atom = (const float*)d_in[4];
  const float* bond = (const float*)d_in[5];
  const float* we0  = (const float*)d_in[6];
  const float* be0  = (const float*)d_in[7];
  const float* w1_0 = (const float*)d_in[8];
  const float* b1_0 = (const float*)d_in[9];
  const float* w2_0 = (const float*)d_in[10];
  const float* b2_0 = (const float*)d_in[11];
  const float* we1  = (const float*)d_in[12];
  const float* be1  = (const float*)d_in[13];
  const float* w1_1 = (const float*)d_in[14];
  const float* b1_1 = (const float*)d_in[15];
  const float* w2_1 = (const float*)d_in[16];
  const float* b2_1 = (const float*)d_in[17];
  const float* l1w  = (const float*)d_in[18];
  const float* l1b  = (const float*)d_in[19];
  const float* l2w  = (const float*)d_in[20];
  const float* l2b  = (const float*)d_in[21];

  char* ws = (char*)d_ws;
  size_t off = 0;
  auto alloc = [&](size_t bytes) -> void* {
    void* p = ws + off;
    off = (off + bytes + 255) & ~(size_t)255;
    return p;
  };
  int* bcursor = (int*)alloc((size_t)NB * 4);
  int* offs    = (int*)alloc((size_t)NN * 4);
  int* cnts    = (int*)alloc((size_t)NN * 4);
  float* et1   = (float*)alloc(16 * 128 * 4);
  unsigned short* M0 = (unsigned short*)alloc((size_t)1904 * 64 * 2);  // bf16
  float* hgf   = (float*)alloc((size_t)NG * 128 * 4);
  unsigned short* w1_0z = (unsigned short*)alloc(64 * 128 * 2);
  unsigned short* w2_0z = (unsigned short*)alloc(128 * 128 * 2);
  unsigned short* w1_1z = (unsigned short*)alloc(128 * 128 * 2);
  unsigned short* w2_1z = (unsigned short*)alloc(128 * 128 * 2);
  unsigned short* l1z   = (unsigned short*)alloc(128 * 128 * 2);
  unsigned short* l2z   = (unsigned short*)alloc(128 * 128 * 2);
  uint2* pairs = (uint2*)alloc((size_t)NB * PS * 8);       // dead after k_fine
  unsigned int* csr0 = (unsigned int*)alloc((size_t)NB * CS * 4);
  unsigned int* csr1 = (unsigned int*)alloc((size_t)NB * CS * 4);
  unsigned short* x1 = (unsigned short*)alloc((size_t)NN * 128 * 2);
  unsigned short* h1 = (unsigned short*)alloc((size_t)NN * 128 * 2);
  unsigned short* h0 = (unsigned short*)pairs;  // 12.8 MB alias: pairs dead before agg0
  unsigned short* x2 = h1;  // in-place mlp1 (wave reads own rows before writing)

  k_prep<<<885, 256, 0, stream>>>(bond, we0, be0, we1, be1, atom, et1, M0, hgf, bcursor,
                                  w1_0, w2_0, w1_1, w2_1, l1w, l2w,
                                  w1_0z, w2_0z, w1_1z, w2_1z, l1z, l2z);
  k_bin<<<(NE + 4095) / 4096, 256, 0, stream>>>(e_src, e_dst, e_attr, x_idx, bcursor, pairs);
  k_fine<<<NB, 256, 0, stream>>>(pairs, bcursor, offs, cnts, csr0, csr1);
  k_agg0<<<NN / 4, 256, 0, stream>>>(x_idx, atom, M0, offs, cnts, csr0, h0);
  k_mlp_t<64><<<(NN + 127) / 128, 256, 0, stream>>>(h0, w1_0z, b1_0, w2_0z, b2_0, x1, NN);
  k_agg1<<<NN / 4, 256, 0, stream>>>(x1, et1, offs, cnts, csr1, h1);
  k_mlp_t<128><<<(NN + 127) / 128, 256, 0, stream>>>(h1, w1_1z, b1_1, w2_1z, b2_1, x2, NN);
  k_pool<<<(((NN + 31) / 32) * 64 + 255) / 256, 256, 0, stream>>>(x2, batch, hgf);
  k_head<<<(NG + 63) / 64, 256, 0, stream>>>(hgf, l1z, l1b, l2z, l2b, (float*)d_out, NG);
}